// Round 7
// baseline (837.179 us; speedup 1.0000x reference)
//
#include <hip/hip_runtime.h>
#include <hip/hip_bf16.h>
#include <hip/hip_cooperative_groups.h>
#include <math.h>

namespace cg = cooperative_groups;

typedef __attribute__((ext_vector_type(8))) short short8;
typedef __attribute__((ext_vector_type(4))) float f32x4;

#define MFMA(a, b, c) __builtin_amdgcn_mfma_f32_16x16x32_bf16(a, b, c, 0, 0, 0)

// ws layout (float offsets), ~9.8 MB total. No atomics; every slab fully
// plain-stored before read. FIXED R3/R5 BUG: XNB is [64][2048] bf16 = 65536
// floats (was mis-sized as 32768, overlapping XN2P/P5 -> NaN garbage).
enum : int {
  WS_XB    = 0,        // [64][2048] bf16 (ushort view)        65536 floats
  WS_X2    = 65536,    // [64] f32 row sumsq of x                 64
  WS_DMIN  = 65600,    // [16][64] f32 per-block d2 minima      1024
  WS_P123  = 66624,    // [4][4096][68] f32 (+[64]=col sumsq) 1114112
  WS_PT    = 1180736,  // [4][64][1024] f32 transposed seg-B   262144
  WS_PROB  = 1442880,  // [64][1024] bf16                       32768
  WS_SEL   = 1475648,  // [64][2048] bf16                       65536
  WS_P4    = 1541184,  // [4][2048][68] f32                    557056
  WS_XNB   = 2098240,  // [64][2048] bf16                       65536
  WS_XN2P  = 2163776,  // [32][64] f32                           2048
  WS_P5    = 2165824,  // [4][1024][68] f32 (+[64]=col sumsq)  278528  -> 2444352
};

__device__ inline short bfs(float f) {
  __hip_bfloat16 h = __float2bfloat16(f);
  return __builtin_bit_cast(short, h);
}
__device__ inline float bf2f(unsigned short u) {
  return __uint_as_float((unsigned)u << 16);
}

__device__ inline void gsync(cg::grid_group& g) {
  __threadfence();
  g.sync();
  __threadfence();
}

__global__ __launch_bounds__(256, 2) void kfused(
    const float* __restrict__ x, const float* __restrict__ centers,
    const float* __restrict__ fcw, const float* __restrict__ fcb,
    const float* __restrict__ fc1w, const float* __restrict__ fc1b,
    const float* __restrict__ cosw, float* __restrict__ out,
    float* __restrict__ ws) {
  cg::grid_group grid = cg::this_grid();
  __shared__ float tile[64][65];
  __shared__ float red[4][64];
  int blk = blockIdx.x, t = threadIdx.x;
  int l = t & 63, w = t >> 6;

  // ======== P1: x -> bf16 XB, row sumsq, slow out ========
  if (blk < 64) {
    int b = blk;
    const float* xr = x + (size_t)b * 2048 + t * 8;
    float4 f0 = *(const float4*)(xr);
    float4 f1 = *(const float4*)(xr + 4);
    short8 h;
    h[0] = bfs(f0.x); h[1] = bfs(f0.y); h[2] = bfs(f0.z); h[3] = bfs(f0.w);
    h[4] = bfs(f1.x); h[5] = bfs(f1.y); h[6] = bfs(f1.z); h[7] = bfs(f1.w);
    *(short8*)((unsigned short*)(ws + WS_XB) + (size_t)b * 2048 + t * 8) = h;
    *(float4*)(out + 64000 + (size_t)b * 2048 + t * 8) = f0;
    *(float4*)(out + 64000 + (size_t)b * 2048 + t * 8 + 4) = f1;
    float s = f0.x*f0.x + f0.y*f0.y + f0.z*f0.z + f0.w*f0.w
            + f1.x*f1.x + f1.y*f1.y + f1.z*f1.z + f1.w*f1.w;
#pragma unroll
    for (int o = 32; o; o >>= 1) s += __shfl_xor(s, o);
    if (l == 0) red[0][w] = s;
    __syncthreads();
    if (t == 0) ws[WS_X2 + b] = red[0][0] + red[0][1] + red[0][2] + red[0][3];
  }
  gsync(grid);

  // ======== P2: G123 = x @ [centers; fc1w; fcw]^T, split-K=4 ========
  {
    int colblk = blk & 127, ksplit = blk >> 7;
    int ln = l & 15, lk = l >> 4;
    int n = colblk * 32 + (w & 1) * 16 + ln;   // 0..4095
    int m0 = (w >> 1) * 32;
    int k0 = ksplit * 512;
    const float* brow;
    if (n < 1024)      brow = centers + (size_t)min(n, 999) * 2048;
    else if (n < 2048) brow = fc1w + (size_t)min(n - 1024, 999) * 2048;
    else               brow = fcw + (size_t)(n - 2048) * 2048;
    const float* bptr = brow + k0 + lk * 8;
    const unsigned short* aptr =
        (const unsigned short*)(ws + WS_XB) + (size_t)(m0 + ln) * 2048 + k0 + lk * 8;
    f32x4 acc0 = {0.f, 0.f, 0.f, 0.f}, acc1 = {0.f, 0.f, 0.f, 0.f};
    float sq = 0.f;
#pragma unroll 4
    for (int ks = 0; ks < 16; ++ks) {
      short8 a0 = *(const short8*)(aptr + ks * 32);
      short8 a1 = *(const short8*)(aptr + 16 * 2048 + ks * 32);
      float4 f0 = *(const float4*)(bptr + ks * 32);
      float4 f1 = *(const float4*)(bptr + ks * 32 + 4);
      sq += f0.x*f0.x + f0.y*f0.y + f0.z*f0.z + f0.w*f0.w
          + f1.x*f1.x + f1.y*f1.y + f1.z*f1.z + f1.w*f1.w;
      short8 bb;
      bb[0] = bfs(f0.x); bb[1] = bfs(f0.y); bb[2] = bfs(f0.z); bb[3] = bfs(f0.w);
      bb[4] = bfs(f1.x); bb[5] = bfs(f1.y); bb[6] = bfs(f1.z); bb[7] = bfs(f1.w);
      acc0 = MFMA(a0, bb, acc0);
      acc1 = MFMA(a1, bb, acc1);
    }
    float* P = ws + WS_P123 + ((size_t)ksplit * 4096 + n) * 68;
    *(f32x4*)(P + m0 + lk * 4) = acc0;
    *(f32x4*)(P + m0 + 16 + lk * 4) = acc1;
    sq += __shfl_xor(sq, 16);
    sq += __shfl_xor(sq, 32);
    if (w < 2 && l < 16) P[64] = sq;   // per-col ||w||^2 partial
    if (n >= 1024 && n < 2048) {       // transposed copy for softmax self-reduce
      int c = n - 1024;
      float* PT = ws + WS_PT + (size_t)ksplit * 64 * 1024 + c;
#pragma unroll
      for (int j = 0; j < 4; ++j) PT[(size_t)(m0 + lk * 4 + j) * 1024] = acc0[j];
#pragma unroll
      for (int j = 0; j < 4; ++j) PT[(size_t)(m0 + 16 + lk * 4 + j) * 1024] = acc1[j];
    }
  }
  gsync(grid);

  // ======== P3: dmin partials (blk<16) | softmax->PROB (16..31) | SEL (32..63)
  if (blk < 16) {
    int n0 = blk * 64;
    const size_t KS = (size_t)4096 * 68;
    float x2 = ws[WS_X2 + l];
    float tmin = 3.0e38f;
    for (int nl = w; nl < 64; nl += 4) {
      int n = n0 + nl;
      if (n < 1000) {
        const float* P = ws + WS_P123 + (size_t)n * 68;
        float v = P[l] + P[KS + l] + P[2*KS + l] + P[3*KS + l];
        float c2 = P[64] + P[KS + 64] + P[2*KS + 64] + P[3*KS + 64];
        tmin = fminf(tmin, fmaxf(x2 - 2.f * v + c2, 0.f));
      }
    }
    red[w][l] = tmin;
    __syncthreads();
    if (t < 64) {
      float m = fminf(fminf(red[0][t], red[1][t]), fminf(red[2][t], red[3][t]));
      ws[WS_DMIN + blk * 64 + t] = m;   // plain store, no atomics
    }
  } else if (blk < 32) {
    int b = (blk - 16) * 4 + w;  // wave per row
    const float* PT = ws + WS_PT;
    float vals[16];
    float m = -3.0e38f;
#pragma unroll
    for (int i = 0; i < 16; ++i) {
      int c = i * 64 + l;
      float v = -3.0e38f;
      if (c < 1000) {
        v = PT[((size_t)0 * 64 + b) * 1024 + c] + PT[((size_t)1 * 64 + b) * 1024 + c]
          + PT[((size_t)2 * 64 + b) * 1024 + c] + PT[((size_t)3 * 64 + b) * 1024 + c]
          + fc1b[c];
      }
      vals[i] = v;
      m = fmaxf(m, v);
    }
#pragma unroll
    for (int o = 32; o; o >>= 1) m = fmaxf(m, __shfl_xor(m, o));
    float s = 0.f;
#pragma unroll
    for (int i = 0; i < 16; ++i) {
      float e = (vals[i] > -1.0e37f) ? __expf(vals[i] - m) : 0.f;
      vals[i] = e;
      s += e;
    }
#pragma unroll
    for (int o = 32; o; o >>= 1) s += __shfl_xor(s, o);
    float inv = 1.0f / s;
    unsigned short* pb = (unsigned short*)(ws + WS_PROB) + (size_t)b * 1024;
#pragma unroll
    for (int i = 0; i < 16; ++i) pb[i * 64 + l] = (unsigned short)bfs(vals[i] * inv);
  } else if (blk < 64) {
    int d0 = (blk - 32) * 64;
    const size_t KS = (size_t)4096 * 68;
    for (int nl = w; nl < 64; nl += 4) {
      int n = 2048 + d0 + nl;
      const float* P = ws + WS_P123 + (size_t)n * 68;
      float v = P[l] + P[KS + l] + P[2*KS + l] + P[3*KS + l];
      tile[nl][l] = tanhf(v + fcb[d0 + nl]);
    }
    __syncthreads();
    unsigned short* sel = (unsigned short*)(ws + WS_SEL);
    for (int r = 0; r < 16; ++r) {
      int m = w * 16 + r;
      sel[(size_t)m * 2048 + d0 + l] = (unsigned short)bfs(tile[l][m]);
    }
  }
  gsync(grid);

  // ======== P4: G4 = prob @ centers, split-K=4 ========
  if (blk < 256) {
    int colblk = blk & 63, ksplit = blk >> 6;
    int ln = l & 15, lk = l >> 4;
    int n = colblk * 32 + (w & 1) * 16 + ln;   // d: 0..2047
    int m0 = (w >> 1) * 32;
    int k0 = ksplit * 256;
    const unsigned short* aptr =
        (const unsigned short*)(ws + WS_PROB) + (size_t)(m0 + ln) * 1024 + k0 + lk * 8;
    f32x4 acc0 = {0.f, 0.f, 0.f, 0.f}, acc1 = {0.f, 0.f, 0.f, 0.f};
    for (int ks = 0; ks < 8; ++ks) {
      short8 a0 = *(const short8*)(aptr + ks * 32);
      short8 a1 = *(const short8*)(aptr + 16 * 1024 + ks * 32);
      int kbase = k0 + ks * 32 + lk * 8;
      short8 bb;
#pragma unroll
      for (int j = 0; j < 8; ++j) {
        int kc = min(kbase + j, 999);
        bb[j] = bfs(centers[(size_t)kc * 2048 + n]);
      }
      acc0 = MFMA(a0, bb, acc0);
      acc1 = MFMA(a1, bb, acc1);
    }
    float* P = ws + WS_P4 + ((size_t)ksplit * 2048 + n) * 68;
    *(f32x4*)(P + m0 + lk * 4) = acc0;
    *(f32x4*)(P + m0 + 16 + lk * 4) = acc1;
  }
  gsync(grid);

  // ======== P5: reduce P4 + conf + fast out + x_new bf16 + ||x_new||^2 ====
  if (blk < 32) {
    int d0 = blk * 64;
    const size_t KS = (size_t)2048 * 68;
    if (t < 64) {   // conf[b] from plain DMIN slab (all 16 rows written in P3)
      float d2 = ws[WS_DMIN + t];
#pragma unroll
      for (int i = 1; i < 16; ++i) d2 = fminf(d2, ws[WS_DMIN + i * 64 + t]);
      red[0][t] = 10.0f * rsqrtf(fmaxf(d2, 1e-20f));
    }
    for (int dl = w; dl < 64; dl += 4) {
      const float* P = ws + WS_P4 + (size_t)(d0 + dl) * 68;
      tile[dl][l] = P[l] + P[KS + l] + P[2*KS + l] + P[3*KS + l];
    }
    __syncthreads();
    const unsigned short* sel = (const unsigned short*)(ws + WS_SEL);
    unsigned short* xnb = (unsigned short*)(ws + WS_XNB);
    for (int r = 0; r < 16; ++r) {
      int b = w * 16 + r;
      float cc = tile[l][b];
      float sv = bf2f(sel[(size_t)b * 2048 + d0 + l]);
      float xv = x[(size_t)b * 2048 + d0 + l];
      float fast = sv * cc;
      out[195072 + (size_t)b * 2048 + d0 + l] = fast;
      float xn = red[0][b] * (xv + fast);
      xnb[(size_t)b * 2048 + d0 + l] = (unsigned short)bfs(xn);
      float sq = xn * xn;
#pragma unroll
      for (int o = 32; o; o >>= 1) sq += __shfl_xor(sq, o);
      if (l == 0) ws[WS_XN2P + blk * 64 + b] = sq;
    }
  }
  gsync(grid);

  // ======== P6: G5 = x_new @ cosw^T + col sumsq, split-K=4 ========
  if (blk < 128) {
    int colblk = blk & 31, ksplit = blk >> 5;
    int ln = l & 15, lk = l >> 4;
    int n = colblk * 32 + (w & 1) * 16 + ln;   // 0..1023
    int m0 = (w >> 1) * 32;
    int k0 = ksplit * 512;
    const float* bptr = cosw + (size_t)min(n, 999) * 2048 + k0 + lk * 8;
    const unsigned short* aptr =
        (const unsigned short*)(ws + WS_XNB) + (size_t)(m0 + ln) * 2048 + k0 + lk * 8;
    f32x4 acc0 = {0.f, 0.f, 0.f, 0.f}, acc1 = {0.f, 0.f, 0.f, 0.f};
    float sq = 0.f;
#pragma unroll 4
    for (int ks = 0; ks < 16; ++ks) {
      short8 a0 = *(const short8*)(aptr + ks * 32);
      short8 a1 = *(const short8*)(aptr + 16 * 2048 + ks * 32);
      float4 f0 = *(const float4*)(bptr + ks * 32);
      float4 f1 = *(const float4*)(bptr + ks * 32 + 4);
      sq += f0.x*f0.x + f0.y*f0.y + f0.z*f0.z + f0.w*f0.w
          + f1.x*f1.x + f1.y*f1.y + f1.z*f1.z + f1.w*f1.w;
      short8 bb;
      bb[0] = bfs(f0.x); bb[1] = bfs(f0.y); bb[2] = bfs(f0.z); bb[3] = bfs(f0.w);
      bb[4] = bfs(f1.x); bb[5] = bfs(f1.y); bb[6] = bfs(f1.z); bb[7] = bfs(f1.w);
      acc0 = MFMA(a0, bb, acc0);
      acc1 = MFMA(a1, bb, acc1);
    }
    float* P = ws + WS_P5 + ((size_t)ksplit * 1024 + n) * 68;
    *(f32x4*)(P + m0 + lk * 4) = acc0;
    *(f32x4*)(P + m0 + 16 + lk * 4) = acc1;
    sq += __shfl_xor(sq, 16);
    sq += __shfl_xor(sq, 32);
    if (w < 2 && l < 16) P[64] = sq;
  }
  gsync(grid);

  // ======== P7: reduce P5 + cosnorm epilogue -> logits ========
  if (blk < 16) {
    int c0 = blk * 64;
    const size_t KS = (size_t)1024 * 68;
    if (t < 64) {
      float s = 0.f;
      for (int i = 0; i < 32; ++i) s += ws[WS_XN2P + i * 64 + t];
      red[0][t] = sqrtf(fmaxf(s, 0.f));
    }
    __syncthreads();
    for (int cl = w; cl < 64; cl += 4) {
      int c = c0 + cl;
      const float* P = ws + WS_P5 + (size_t)c * 68;
      float v = P[l] + P[KS + l] + P[2*KS + l] + P[3*KS + l];
      float w2 = P[64] + P[KS + 64] + P[2*KS + 64] + P[3*KS + 64];
      tile[cl][l] = 16.0f * v * rsqrtf(fmaxf(w2, 1e-30f)) / (1.0f + red[0][l]);
    }
    __syncthreads();
    for (int r = 0; r < 16; ++r) {
      int b = w * 16 + r;
      int c = c0 + l;
      if (c < 1000) out[(size_t)b * 1000 + c] = tile[l][b];
    }
  }
}

extern "C" void kernel_launch(void* const* d_in, const int* in_sizes, int n_in,
                              void* d_out, int out_size, void* d_ws, size_t ws_size,
                              hipStream_t stream) {
  const float* x       = (const float*)d_in[0];
  const float* centers = (const float*)d_in[2];
  const float* fcw     = (const float*)d_in[4];
  const float* fcb     = (const float*)d_in[5];
  const float* fc1w    = (const float*)d_in[6];
  const float* fc1b    = (const float*)d_in[7];
  const float* cosw    = (const float*)d_in[8];
  float* out = (float*)d_out;
  float* ws  = (float*)d_ws;

  void* args[] = {(void*)&x, (void*)&centers, (void*)&fcw, (void*)&fcb,
                  (void*)&fc1w, (void*)&fc1b, (void*)&cosw, (void*)&out, (void*)&ws};
  hipLaunchCooperativeKernel((const void*)kfused, dim3(512), dim3(256), args, 0, stream);
}

// Round 8
// 94.075 us; speedup vs baseline: 8.8990x; 8.8990x over previous
//
#include <hip/hip_runtime.h>
#include <hip/hip_bf16.h>
#include <math.h>

typedef __attribute__((ext_vector_type(8))) short short8;
typedef __attribute__((ext_vector_type(4))) float f32x4;

#define MFMA(a, b, c) __builtin_amdgcn_mfma_f32_16x16x32_bf16(a, b, c, 0, 0, 0)

// ws layout (float offsets), ~11 MB. Every slab fully plain-stored before read
// in a strictly earlier launch (stream-ordered). No atomics.
enum : int {
  WS_XB    = 0,        // [64][2048] bf16 (ushort view)        65536 floats
  WS_X2    = 65536,    // [64] f32 row sumsq of x                 64
  WS_DMIN  = 65600,    // [16][64] f32 per-block d2 minima      1024
  WS_P123  = 66624,    // [4][4096][68] f32 (+[64]=col sumsq) 1114112
  WS_PT    = 1180736,  // [4][64][1024] f32 transposed seg-B   262144
  WS_PROB  = 1442880,  // [64][1024] bf16                       32768
  WS_SEL   = 1475648,  // [64][2048] bf16                       65536
  WS_P4    = 1541184,  // [4][2048][68] f32                    557056
  WS_XNB   = 2098240,  // [64][2048] bf16                       65536
  WS_XN2P  = 2163776,  // [32][64] f32                           2048
  WS_P5    = 2165824,  // [8][1024][68] f32 (+[64]=col sumsq)  557056 -> 2722880
};

__device__ inline short bfs(float f) {
  __hip_bfloat16 h = __float2bfloat16(f);
  return __builtin_bit_cast(short, h);
}
__device__ inline float bf2f(unsigned short u) {
  return __uint_as_float((unsigned)u << 16);
}

// ---- ka: x -> bf16 XB, row sumsq, slow out ----
__global__ __launch_bounds__(256) void ka(const float* __restrict__ x,
                                          float* __restrict__ out,
                                          float* __restrict__ ws) {
  __shared__ float red4[4];
  int b = blockIdx.x, t = threadIdx.x;
  int l = t & 63, w = t >> 6;
  const float* xr = x + (size_t)b * 2048 + t * 8;
  float4 f0 = *(const float4*)(xr);
  float4 f1 = *(const float4*)(xr + 4);
  short8 h;
  h[0] = bfs(f0.x); h[1] = bfs(f0.y); h[2] = bfs(f0.z); h[3] = bfs(f0.w);
  h[4] = bfs(f1.x); h[5] = bfs(f1.y); h[6] = bfs(f1.z); h[7] = bfs(f1.w);
  *(short8*)((unsigned short*)(ws + WS_XB) + (size_t)b * 2048 + t * 8) = h;
  *(float4*)(out + 64000 + (size_t)b * 2048 + t * 8) = f0;
  *(float4*)(out + 64000 + (size_t)b * 2048 + t * 8 + 4) = f1;
  float s = f0.x*f0.x + f0.y*f0.y + f0.z*f0.z + f0.w*f0.w
          + f1.x*f1.x + f1.y*f1.y + f1.z*f1.z + f1.w*f1.w;
#pragma unroll
  for (int o = 32; o; o >>= 1) s += __shfl_xor(s, o);
  if (l == 0) red4[w] = s;
  __syncthreads();
  if (t == 0) ws[WS_X2 + b] = red4[0] + red4[1] + red4[2] + red4[3];
}

// ---- kb: G123 = x @ [centers; fc1w; fcw]^T, split-K=4, + PT + col sumsq ----
__global__ __launch_bounds__(256) void kb(const float* __restrict__ centers,
                                          const float* __restrict__ fc1w,
                                          const float* __restrict__ fcw,
                                          float* __restrict__ ws) {
  int blk = blockIdx.x, t = threadIdx.x;
  int l = t & 63, w = t >> 6;
  int colblk = blk & 127, ksplit = blk >> 7;
  int ln = l & 15, lk = l >> 4;
  int n = colblk * 32 + (w & 1) * 16 + ln;   // 0..4095
  int m0 = (w >> 1) * 32;
  int k0 = ksplit * 512;
  const float* brow;
  if (n < 1024)      brow = centers + (size_t)min(n, 999) * 2048;
  else if (n < 2048) brow = fc1w + (size_t)min(n - 1024, 999) * 2048;
  else               brow = fcw + (size_t)(n - 2048) * 2048;
  const float* bptr = brow + k0 + lk * 8;
  const unsigned short* aptr =
      (const unsigned short*)(ws + WS_XB) + (size_t)(m0 + ln) * 2048 + k0 + lk * 8;
  f32x4 acc0 = {0.f, 0.f, 0.f, 0.f}, acc1 = {0.f, 0.f, 0.f, 0.f};
  float sq = 0.f;
#pragma unroll 4
  for (int ks = 0; ks < 16; ++ks) {
    short8 a0 = *(const short8*)(aptr + ks * 32);
    short8 a1 = *(const short8*)(aptr + 16 * 2048 + ks * 32);
    float4 f0 = *(const float4*)(bptr + ks * 32);
    float4 f1 = *(const float4*)(bptr + ks * 32 + 4);
    sq += f0.x*f0.x + f0.y*f0.y + f0.z*f0.z + f0.w*f0.w
        + f1.x*f1.x + f1.y*f1.y + f1.z*f1.z + f1.w*f1.w;
    short8 bb;
    bb[0] = bfs(f0.x); bb[1] = bfs(f0.y); bb[2] = bfs(f0.z); bb[3] = bfs(f0.w);
    bb[4] = bfs(f1.x); bb[5] = bfs(f1.y); bb[6] = bfs(f1.z); bb[7] = bfs(f1.w);
    acc0 = MFMA(a0, bb, acc0);
    acc1 = MFMA(a1, bb, acc1);
  }
  float* P = ws + WS_P123 + ((size_t)ksplit * 4096 + n) * 68;
  *(f32x4*)(P + m0 + lk * 4) = acc0;
  *(f32x4*)(P + m0 + 16 + lk * 4) = acc1;
  sq += __shfl_xor(sq, 16);
  sq += __shfl_xor(sq, 32);
  if (w < 2 && l < 16) P[64] = sq;   // per-col ||w||^2 partial
  if (n >= 1024 && n < 2048) {       // transposed copy for softmax self-reduce
    int c = n - 1024;
    float* PT = ws + WS_PT + (size_t)ksplit * 64 * 1024 + c;
#pragma unroll
    for (int j = 0; j < 4; ++j) PT[(size_t)(m0 + lk * 4 + j) * 1024] = acc0[j];
#pragma unroll
    for (int j = 0; j < 4; ++j) PT[(size_t)(m0 + 16 + lk * 4 + j) * 1024] = acc1[j];
  }
}

// ---- kc: dmin partials (blk<16) | softmax(PT)->PROB (16..31) | SEL (32..63) ----
__global__ __launch_bounds__(256) void kc(const float* __restrict__ fc1b,
                                          const float* __restrict__ fcb,
                                          float* __restrict__ ws) {
  __shared__ float tile[64][65];
  __shared__ float red[4][64];
  int blk = blockIdx.x, t = threadIdx.x;
  int l = t & 63, w = t >> 6;
  if (blk < 16) {
    int n0 = blk * 64;
    const size_t KS = (size_t)4096 * 68;
    float x2 = ws[WS_X2 + l];
    float tmin = 3.0e38f;
    for (int nl = w; nl < 64; nl += 4) {
      int n = n0 + nl;
      if (n < 1000) {
        const float* P = ws + WS_P123 + (size_t)n * 68;
        float v = P[l] + P[KS + l] + P[2*KS + l] + P[3*KS + l];
        float c2 = P[64] + P[KS + 64] + P[2*KS + 64] + P[3*KS + 64];
        tmin = fminf(tmin, fmaxf(x2 - 2.f * v + c2, 0.f));
      }
    }
    red[w][l] = tmin;
    __syncthreads();
    if (t < 64) {
      float m = fminf(fminf(red[0][t], red[1][t]), fminf(red[2][t], red[3][t]));
      ws[WS_DMIN + blk * 64 + t] = m;
    }
  } else if (blk < 32) {
    int b = (blk - 16) * 4 + w;  // wave per row
    const float* PT = ws + WS_PT;
    float vals[16];
    float m = -3.0e38f;
#pragma unroll
    for (int i = 0; i < 16; ++i) {
      int c = i * 64 + l;
      float v = -3.0e38f;
      if (c < 1000) {
        v = PT[((size_t)0 * 64 + b) * 1024 + c] + PT[((size_t)1 * 64 + b) * 1024 + c]
          + PT[((size_t)2 * 64 + b) * 1024 + c] + PT[((size_t)3 * 64 + b) * 1024 + c]
          + fc1b[c];
      }
      vals[i] = v;
      m = fmaxf(m, v);
    }
#pragma unroll
    for (int o = 32; o; o >>= 1) m = fmaxf(m, __shfl_xor(m, o));
    float s = 0.f;
#pragma unroll
    for (int i = 0; i < 16; ++i) {
      float e = (vals[i] > -1.0e37f) ? __expf(vals[i] - m) : 0.f;
      vals[i] = e;
      s += e;
    }
#pragma unroll
    for (int o = 32; o; o >>= 1) s += __shfl_xor(s, o);
    float inv = 1.0f / s;
    unsigned short* pb = (unsigned short*)(ws + WS_PROB) + (size_t)b * 1024;
#pragma unroll
    for (int i = 0; i < 16; ++i) pb[i * 64 + l] = (unsigned short)bfs(vals[i] * inv);
  } else {
    int d0 = (blk - 32) * 64;
    const size_t KS = (size_t)4096 * 68;
    for (int nl = w; nl < 64; nl += 4) {
      int n = 2048 + d0 + nl;
      const float* P = ws + WS_P123 + (size_t)n * 68;
      float v = P[l] + P[KS + l] + P[2*KS + l] + P[3*KS + l];
      tile[nl][l] = tanhf(v + fcb[d0 + nl]);
    }
    __syncthreads();
    unsigned short* sel = (unsigned short*)(ws + WS_SEL);
    for (int r = 0; r < 16; ++r) {
      int m = w * 16 + r;
      sel[(size_t)m * 2048 + d0 + l] = (unsigned short)bfs(tile[l][m]);
    }
  }
}

// ---- kd: G4 = prob @ centers, split-K=4 ----
__global__ __launch_bounds__(256) void kd(const float* __restrict__ centers,
                                          float* __restrict__ ws) {
  int blk = blockIdx.x, t = threadIdx.x;
  int w = t >> 6, l = t & 63;
  int colblk = blk & 63, ksplit = blk >> 6;
  int ln = l & 15, lk = l >> 4;
  int n = colblk * 32 + (w & 1) * 16 + ln;   // d: 0..2047
  int m0 = (w >> 1) * 32;
  int k0 = ksplit * 256;
  const unsigned short* aptr =
      (const unsigned short*)(ws + WS_PROB) + (size_t)(m0 + ln) * 1024 + k0 + lk * 8;
  f32x4 acc0 = {0.f, 0.f, 0.f, 0.f}, acc1 = {0.f, 0.f, 0.f, 0.f};
  for (int ks = 0; ks < 8; ++ks) {
    short8 a0 = *(const short8*)(aptr + ks * 32);
    short8 a1 = *(const short8*)(aptr + 16 * 1024 + ks * 32);
    int kbase = k0 + ks * 32 + lk * 8;
    short8 bb;
#pragma unroll
    for (int j = 0; j < 8; ++j) {
      int kc2 = min(kbase + j, 999);
      bb[j] = bfs(centers[(size_t)kc2 * 2048 + n]);
    }
    acc0 = MFMA(a0, bb, acc0);
    acc1 = MFMA(a1, bb, acc1);
  }
  float* P = ws + WS_P4 + ((size_t)ksplit * 2048 + n) * 68;
  *(f32x4*)(P + m0 + lk * 4) = acc0;
  *(f32x4*)(P + m0 + 16 + lk * 4) = acc1;
}

// ---- ke: conf(DMIN) + reduce P4 + fast out + x_new bf16 + ||x_new||^2 ----
__global__ __launch_bounds__(256) void ke(const float* __restrict__ x,
                                          float* __restrict__ out,
                                          float* __restrict__ ws) {
  __shared__ float tile[64][65];
  __shared__ float conf[64];
  int blk = blockIdx.x, t = threadIdx.x, l = t & 63, w = t >> 6;
  int d0 = blk * 64;
  const size_t KS = (size_t)2048 * 68;
  if (t < 64) {
    float d2 = ws[WS_DMIN + t];
#pragma unroll
    for (int i = 1; i < 16; ++i) d2 = fminf(d2, ws[WS_DMIN + i * 64 + t]);
    conf[t] = 10.0f * rsqrtf(fmaxf(d2, 1e-20f));
  }
  for (int dl = w; dl < 64; dl += 4) {
    const float* P = ws + WS_P4 + (size_t)(d0 + dl) * 68;
    tile[dl][l] = P[l] + P[KS + l] + P[2*KS + l] + P[3*KS + l];
  }
  __syncthreads();
  const unsigned short* sel = (const unsigned short*)(ws + WS_SEL);
  unsigned short* xnb = (unsigned short*)(ws + WS_XNB);
  for (int r = 0; r < 16; ++r) {
    int b = w * 16 + r;
    float cc = tile[l][b];
    float sv = bf2f(sel[(size_t)b * 2048 + d0 + l]);
    float xv = x[(size_t)b * 2048 + d0 + l];
    float fast = sv * cc;
    out[195072 + (size_t)b * 2048 + d0 + l] = fast;
    float xn = conf[b] * (xv + fast);
    xnb[(size_t)b * 2048 + d0 + l] = (unsigned short)bfs(xn);
    float sq = xn * xn;
#pragma unroll
    for (int o = 32; o; o >>= 1) sq += __shfl_xor(sq, o);
    if (l == 0) ws[WS_XN2P + blk * 64 + b] = sq;
  }
}

// ---- kf: G5 = x_new @ cosw^T + col sumsq, split-K=8; grid 256 = 32 x 8 ----
__global__ __launch_bounds__(256) void kf(const float* __restrict__ cosw,
                                          float* __restrict__ ws) {
  int blk = blockIdx.x, t = threadIdx.x;
  int w = t >> 6, l = t & 63;
  int colblk = blk & 31, ksplit = blk >> 5;   // 0..31 x 0..7
  int ln = l & 15, lk = l >> 4;
  int n = colblk * 32 + (w & 1) * 16 + ln;    // 0..1023
  int m0 = (w >> 1) * 32;
  int k0 = ksplit * 256;
  const float* bptr = cosw + (size_t)min(n, 999) * 2048 + k0 + lk * 8;
  const unsigned short* aptr =
      (const unsigned short*)(ws + WS_XNB) + (size_t)(m0 + ln) * 2048 + k0 + lk * 8;
  f32x4 acc0 = {0.f, 0.f, 0.f, 0.f}, acc1 = {0.f, 0.f, 0.f, 0.f};
  float sq = 0.f;
#pragma unroll
  for (int ks = 0; ks < 8; ++ks) {
    short8 a0 = *(const short8*)(aptr + ks * 32);
    short8 a1 = *(const short8*)(aptr + 16 * 2048 + ks * 32);
    float4 f0 = *(const float4*)(bptr + ks * 32);
    float4 f1 = *(const float4*)(bptr + ks * 32 + 4);
    sq += f0.x*f0.x + f0.y*f0.y + f0.z*f0.z + f0.w*f0.w
        + f1.x*f1.x + f1.y*f1.y + f1.z*f1.z + f1.w*f1.w;
    short8 bb;
    bb[0] = bfs(f0.x); bb[1] = bfs(f0.y); bb[2] = bfs(f0.z); bb[3] = bfs(f0.w);
    bb[4] = bfs(f1.x); bb[5] = bfs(f1.y); bb[6] = bfs(f1.z); bb[7] = bfs(f1.w);
    acc0 = MFMA(a0, bb, acc0);
    acc1 = MFMA(a1, bb, acc1);
  }
  float* P = ws + WS_P5 + ((size_t)ksplit * 1024 + n) * 68;
  *(f32x4*)(P + m0 + lk * 4) = acc0;
  *(f32x4*)(P + m0 + 16 + lk * 4) = acc1;
  sq += __shfl_xor(sq, 16);
  sq += __shfl_xor(sq, 32);
  if (w < 2 && l < 16) P[64] = sq;
}

// ---- kg: reduce P5 (8 splits) + cosnorm epilogue -> logits ----
__global__ __launch_bounds__(256) void kg(float* __restrict__ out,
                                          const float* __restrict__ ws) {
  __shared__ float tile[64][65];
  __shared__ float nr[64];
  int blk = blockIdx.x, t = threadIdx.x, l = t & 63, w = t >> 6;
  int c0 = blk * 64;
  const size_t KS = (size_t)1024 * 68;
  if (t < 64) {
    float s = 0.f;
    for (int i = 0; i < 32; ++i) s += ws[WS_XN2P + i * 64 + t];
    nr[t] = sqrtf(fmaxf(s, 0.f));
  }
  __syncthreads();
  for (int cl = w; cl < 64; cl += 4) {
    int c = c0 + cl;
    const float* P = ws + WS_P5 + (size_t)c * 68;
    float v = 0.f, w2 = 0.f;
#pragma unroll
    for (int j = 0; j < 8; ++j) {
      v  += P[(size_t)j * KS + l];
      w2 += P[(size_t)j * KS + 64];
    }
    tile[cl][l] = 16.0f * v * rsqrtf(fmaxf(w2, 1e-30f)) / (1.0f + nr[l]);
  }
  __syncthreads();
  for (int r = 0; r < 16; ++r) {
    int b = w * 16 + r;
    int c = c0 + l;
    if (c < 1000) out[(size_t)b * 1000 + c] = tile[l][b];
  }
}

extern "C" void kernel_launch(void* const* d_in, const int* in_sizes, int n_in,
                              void* d_out, int out_size, void* d_ws, size_t ws_size,
                              hipStream_t stream) {
  const float* x       = (const float*)d_in[0];
  const float* centers = (const float*)d_in[2];
  const float* fcw     = (const float*)d_in[4];
  const float* fcb     = (const float*)d_in[5];
  const float* fc1w    = (const float*)d_in[6];
  const float* fc1b    = (const float*)d_in[7];
  const float* cosw    = (const float*)d_in[8];
  float* out = (float*)d_out;
  float* ws  = (float*)d_ws;

  hipLaunchKernelGGL(ka, dim3(64),  dim3(256), 0, stream, x, out, ws);
  hipLaunchKernelGGL(kb, dim3(512), dim3(256), 0, stream, centers, fc1w, fcw, ws);
  hipLaunchKernelGGL(kc, dim3(64),  dim3(256), 0, stream, fc1b, fcb, ws);
  hipLaunchKernelGGL(kd, dim3(256), dim3(256), 0, stream, centers, ws);
  hipLaunchKernelGGL(ke, dim3(32),  dim3(256), 0, stream, x, out, ws);
  hipLaunchKernelGGL(kf, dim3(256), dim3(256), 0, stream, cosw, ws);
  hipLaunchKernelGGL(kg, dim3(16),  dim3(256), 0, stream, out, ws);
}

// Round 9
// 78.110 us; speedup vs baseline: 10.7179x; 1.2044x over previous
//
#include <hip/hip_runtime.h>
#include <hip/hip_bf16.h>
#include <math.h>

typedef __attribute__((ext_vector_type(8))) short short8;
typedef __attribute__((ext_vector_type(4))) float f32x4;

#define MFMA(a, b, c) __builtin_amdgcn_mfma_f32_16x16x32_bf16(a, b, c, 0, 0, 0)

// ws layout (float offsets), ~11.2 MB
enum : int {
  WS_XB   = 0,        // [64][2048] bf16 (ushort view)       65536
  WS_X2   = 65536,    // [64] f32 row sumsq of x                64
  WS_D2MIN= 65600,    // [64] uint bits                         64
  WS_CONF = 65664,    // [64]                                   64
  WS_P123 = 65728,    // [8][4096][68] f32 (+[64]=col sumsq) 2228224
  WS_L1   = 2293952,  // [64][1024] f32 logits_stage1          65536
  WS_PROB = 2359488,  // [64][1024] bf16                       32768
  WS_SEL  = 2392256,  // [64][2048] bf16                       65536
  WS_XNB  = 2457792,  // [64][2048] bf16                       65536
  WS_XN2P = 2523328,  // [128][64] f32 partials ||x_new||^2     8192
  WS_P5   = 2531520,  // [4][1024][68] f32 (+[64]=col sumsq)  278528 -> 2810048
};

__device__ inline short bfs(float f) {
  __hip_bfloat16 h = __float2bfloat16(f);
  return __builtin_bit_cast(short, h);
}
__device__ inline float bf2f(unsigned short u) {
  return __uint_as_float((unsigned)u << 16);
}

// ---- K1: x -> bf16, x row sumsq, slow_feature out, d2min init (R2-proven) ----
__global__ __launch_bounds__(256) void k1(const float* __restrict__ x,
                                          float* __restrict__ out,
                                          float* __restrict__ ws) {
  __shared__ float red[4];
  int b = blockIdx.x, t = threadIdx.x;
  int l = t & 63, w = t >> 6;
  const float* xr = x + (size_t)b * 2048 + t * 8;
  float4 f0 = *(const float4*)(xr);
  float4 f1 = *(const float4*)(xr + 4);
  short8 h;
  h[0] = bfs(f0.x); h[1] = bfs(f0.y); h[2] = bfs(f0.z); h[3] = bfs(f0.w);
  h[4] = bfs(f1.x); h[5] = bfs(f1.y); h[6] = bfs(f1.z); h[7] = bfs(f1.w);
  *(short8*)((unsigned short*)(ws + WS_XB) + (size_t)b * 2048 + t * 8) = h;
  *(float4*)(out + 64000 + (size_t)b * 2048 + t * 8) = f0;
  *(float4*)(out + 64000 + (size_t)b * 2048 + t * 8 + 4) = f1;
  float s = f0.x*f0.x + f0.y*f0.y + f0.z*f0.z + f0.w*f0.w
          + f1.x*f1.x + f1.y*f1.y + f1.z*f1.z + f1.w*f1.w;
#pragma unroll
  for (int o = 32; o; o >>= 1) s += __shfl_xor(s, o);
  if (l == 0) red[w] = s;
  __syncthreads();
  if (t == 0) ws[WS_X2 + b] = red[0] + red[1] + red[2] + red[3];
  if (b == 0 && t < 64) ((unsigned*)(ws + WS_D2MIN))[t] = 0x7f800000u;  // +inf
}

// ---- K2: G123 = x @ [centers; fc1w; fcw]^T, split-K=8 (1024 blocks) ----
__global__ __launch_bounds__(256) void k2(const float* __restrict__ centers,
                                          const float* __restrict__ fc1w,
                                          const float* __restrict__ fcw,
                                          float* __restrict__ ws) {
  int blk = blockIdx.x, t = threadIdx.x;
  int w = t >> 6, l = t & 63;
  int colblk = blk & 127, ksplit = blk >> 7;   // 0..127 x 0..7
  int ln = l & 15, lk = l >> 4;
  int n = colblk * 32 + (w & 1) * 16 + ln;     // 0..4095
  int m0 = (w >> 1) * 32;
  int k0 = ksplit * 256;
  const float* brow;
  if (n < 1024)      brow = centers + (size_t)min(n, 999) * 2048;
  else if (n < 2048) brow = fc1w + (size_t)min(n - 1024, 999) * 2048;
  else               brow = fcw + (size_t)(n - 2048) * 2048;
  const float* bptr = brow + k0 + lk * 8;
  const unsigned short* aptr =
      (const unsigned short*)(ws + WS_XB) + (size_t)(m0 + ln) * 2048 + k0 + lk * 8;
  f32x4 acc0 = {0.f, 0.f, 0.f, 0.f}, acc1 = {0.f, 0.f, 0.f, 0.f};
  float sq = 0.f;
#pragma unroll 4
  for (int ks = 0; ks < 8; ++ks) {
    short8 a0 = *(const short8*)(aptr + ks * 32);
    short8 a1 = *(const short8*)(aptr + 16 * 2048 + ks * 32);
    float4 f0 = *(const float4*)(bptr + ks * 32);
    float4 f1 = *(const float4*)(bptr + ks * 32 + 4);
    sq += f0.x*f0.x + f0.y*f0.y + f0.z*f0.z + f0.w*f0.w
        + f1.x*f1.x + f1.y*f1.y + f1.z*f1.z + f1.w*f1.w;
    short8 bb;
    bb[0] = bfs(f0.x); bb[1] = bfs(f0.y); bb[2] = bfs(f0.z); bb[3] = bfs(f0.w);
    bb[4] = bfs(f1.x); bb[5] = bfs(f1.y); bb[6] = bfs(f1.z); bb[7] = bfs(f1.w);
    acc0 = MFMA(a0, bb, acc0);
    acc1 = MFMA(a1, bb, acc1);
  }
  float* P = ws + WS_P123 + ((size_t)ksplit * 4096 + n) * 68;
  *(f32x4*)(P + m0 + lk * 4) = acc0;
  *(f32x4*)(P + m0 + 16 + lk * 4) = acc1;
  sq += __shfl_xor(sq, 16);
  sq += __shfl_xor(sq, 32);
  if (w < 2 && l < 16) P[64] = sq;   // per-col ||w||^2 partial
}

// ---- K3: reduce P123 (8 splits) -> d2min / L1 / SEL=tanh (R2 body, 8-way) ----
__global__ __launch_bounds__(256) void k3(const float* __restrict__ fc1b,
                                          const float* __restrict__ fcb,
                                          float* __restrict__ ws) {
  __shared__ float tile[64][65];
  __shared__ float red[4][64];
  int blk = blockIdx.x, t = threadIdx.x;
  int l = t & 63, w = t >> 6;
  int n0 = blk * 64;
  const size_t KS = (size_t)4096 * 68;
  float x2 = ws[WS_X2 + l];
  float tmin = 3.0e38f;
  for (int nl = w; nl < 64; nl += 4) {
    int n = n0 + nl;
    const float* P = ws + WS_P123 + (size_t)n * 68;
    float v = 0.f;
#pragma unroll
    for (int j = 0; j < 8; ++j) v += P[(size_t)j * KS + l];
    if (n < 1024) {
      if (n < 1000) {
        float c2 = 0.f;
#pragma unroll
        for (int j = 0; j < 8; ++j) c2 += P[(size_t)j * KS + 64];
        float d2 = fmaxf(x2 - 2.f * v + c2, 0.f);
        tmin = fminf(tmin, d2);
      }
    } else if (n < 2048) {
      int c = n - 1024;
      tile[nl][l] = (c < 1000) ? v + fc1b[c] : 0.f;
    } else {
      tile[nl][l] = tanhf(v + fcb[n - 2048]);
    }
  }
  if (n0 < 1024) {
    red[w][l] = tmin;
    __syncthreads();
    if (t < 64) {
      float m = fminf(fminf(red[0][t], red[1][t]), fminf(red[2][t], red[3][t]));
      atomicMin((unsigned*)(ws + WS_D2MIN) + t, __float_as_uint(m));
    }
  } else if (n0 < 2048) {
    __syncthreads();
    int c0 = n0 - 1024;
    for (int r = 0; r < 16; ++r) {
      int m = w * 16 + r;
      ws[WS_L1 + (size_t)m * 1024 + c0 + l] = tile[l][m];
    }
  } else {
    __syncthreads();
    int d0 = n0 - 2048;
    unsigned short* sel = (unsigned short*)(ws + WS_SEL);
    for (int r = 0; r < 16; ++r) {
      int m = w * 16 + r;
      sel[(size_t)m * 2048 + d0 + l] = (unsigned short)bfs(tile[l][m]);
    }
  }
}

// ---- K4: confidence + row softmax -> PROB bf16 (R2-proven) ----
__global__ __launch_bounds__(256) void k4(float* __restrict__ ws) {
  int t = threadIdx.x, l = t & 63, w = t >> 6;
  int b = blockIdx.x * 4 + w;
  if (blockIdx.x == 0 && t < 64) {
    float d2 = __uint_as_float(((unsigned*)(ws + WS_D2MIN))[t]);
    ws[WS_CONF + t] = 10.0f / sqrtf(d2);
  }
  const float* L = ws + WS_L1 + (size_t)b * 1024;
  float vals[16];
  float m = -3.0e38f;
#pragma unroll
  for (int i = 0; i < 16; ++i) {
    int c = i * 64 + l;
    float v = (c < 1000) ? L[c] : -3.0e38f;
    vals[i] = v;
    m = fmaxf(m, v);
  }
#pragma unroll
  for (int o = 32; o; o >>= 1) m = fmaxf(m, __shfl_xor(m, o));
  float s = 0.f;
#pragma unroll
  for (int i = 0; i < 16; ++i) {
    float e = (vals[i] > -1.0e37f) ? __expf(vals[i] - m) : 0.f;
    vals[i] = e;
    s += e;
  }
#pragma unroll
  for (int o = 32; o; o >>= 1) s += __shfl_xor(s, o);
  float inv = 1.0f / s;
  unsigned short* pb = (unsigned short*)(ws + WS_PROB) + (size_t)b * 1024;
#pragma unroll
  for (int i = 0; i < 16; ++i) pb[i * 64 + l] = (unsigned short)bfs(vals[i] * inv);
}

// ---- KDE: G4 full-K (intra-block K-split over 4 waves) + fused x_new epilogue
// 256 blocks = 128 col-groups (16 d each) x 2 m-halves (32 b each)
__global__ __launch_bounds__(256) void kde(const float* __restrict__ centers,
                                           const float* __restrict__ x,
                                           float* __restrict__ out,
                                           float* __restrict__ ws) {
  __shared__ f32x4 sacc[4][2][64];   // 8 KB
  int blk = blockIdx.x, t = threadIdx.x;
  int w = t >> 6, l = t & 63;
  int cs = blk >> 1, mh = blk & 1;
  int d0 = cs * 16, m0 = mh * 32;
  int ln = l & 15, lk = l >> 4;
  int k0 = w * 256;
  const unsigned short* aptr =
      (const unsigned short*)(ws + WS_PROB) + (size_t)(m0 + ln) * 1024 + k0 + lk * 8;
  f32x4 acc0 = {0.f, 0.f, 0.f, 0.f}, acc1 = {0.f, 0.f, 0.f, 0.f};
  for (int ks = 0; ks < 8; ++ks) {
    short8 a0 = *(const short8*)(aptr + ks * 32);
    short8 a1 = *(const short8*)(aptr + 16 * 1024 + ks * 32);
    int kbase = k0 + ks * 32 + lk * 8;
    short8 bb;
#pragma unroll
    for (int j = 0; j < 8; ++j) {
      int kc = min(kbase + j, 999);
      bb[j] = bfs(centers[(size_t)kc * 2048 + d0 + ln]);
    }
    acc0 = MFMA(a0, bb, acc0);
    acc1 = MFMA(a1, bb, acc1);
  }
  sacc[w][0][l] = acc0;
  sacc[w][1][l] = acc1;
  __syncthreads();
  if (w == 0) {
    f32x4 r0 = sacc[0][0][l], r1 = sacc[0][1][l];
#pragma unroll
    for (int i = 1; i < 4; ++i) {
      f32x4 u0 = sacc[i][0][l], u1 = sacc[i][1][l];
      r0.x += u0.x; r0.y += u0.y; r0.z += u0.z; r0.w += u0.w;
      r1.x += u1.x; r1.y += u1.y; r1.z += u1.z; r1.w += u1.w;
    }
    const unsigned short* sel = (const unsigned short*)(ws + WS_SEL);
    unsigned short* xnb = (unsigned short*)(ws + WS_XNB);
    float rr[8] = {r0.x, r0.y, r0.z, r0.w, r1.x, r1.y, r1.z, r1.w};
#pragma unroll
    for (int q = 0; q < 8; ++q) {
      int b = m0 + (q >> 2) * 16 + lk * 4 + (q & 3);
      int d = d0 + ln;
      float cc = rr[q];
      float sv = bf2f(sel[(size_t)b * 2048 + d]);
      float xv = x[(size_t)b * 2048 + d];
      float fast = sv * cc;
      out[195072 + (size_t)b * 2048 + d] = fast;
      float xn = ws[WS_CONF + b] * (xv + fast);
      xnb[(size_t)b * 2048 + d] = (unsigned short)bfs(xn);
      float sq = xn * xn;
      sq += __shfl_xor(sq, 1);
      sq += __shfl_xor(sq, 2);
      sq += __shfl_xor(sq, 4);
      sq += __shfl_xor(sq, 8);
      if (ln == 0) ws[WS_XN2P + cs * 64 + b] = sq;  // partial over this d-group
    }
  }
}

// ---- K7: G5 = x_new @ cosw^T + ||w||^2 partials; grid 128 = 32 x 4 (R2) ----
__global__ __launch_bounds__(256) void k7(const float* __restrict__ cosw,
                                          float* __restrict__ ws) {
  int blk = blockIdx.x, t = threadIdx.x;
  int w = t >> 6, l = t & 63;
  int colblk = blk & 31, ksplit = blk >> 5;
  int ln = l & 15, lk = l >> 4;
  int n = colblk * 32 + (w & 1) * 16 + ln;   // 0..1023
  int m0 = (w >> 1) * 32;
  int k0 = ksplit * 512;
  const float* bptr = cosw + (size_t)min(n, 999) * 2048 + k0 + lk * 8;
  const unsigned short* aptr =
      (const unsigned short*)(ws + WS_XNB) + (size_t)(m0 + ln) * 2048 + k0 + lk * 8;
  f32x4 acc0 = {0.f, 0.f, 0.f, 0.f}, acc1 = {0.f, 0.f, 0.f, 0.f};
  float sq = 0.f;
#pragma unroll 4
  for (int ks = 0; ks < 16; ++ks) {
    short8 a0 = *(const short8*)(aptr + ks * 32);
    short8 a1 = *(const short8*)(aptr + 16 * 2048 + ks * 32);
    float4 f0 = *(const float4*)(bptr + ks * 32);
    float4 f1 = *(const float4*)(bptr + ks * 32 + 4);
    sq += f0.x*f0.x + f0.y*f0.y + f0.z*f0.z + f0.w*f0.w
        + f1.x*f1.x + f1.y*f1.y + f1.z*f1.z + f1.w*f1.w;
    short8 bb;
    bb[0] = bfs(f0.x); bb[1] = bfs(f0.y); bb[2] = bfs(f0.z); bb[3] = bfs(f0.w);
    bb[4] = bfs(f1.x); bb[5] = bfs(f1.y); bb[6] = bfs(f1.z); bb[7] = bfs(f1.w);
    acc0 = MFMA(a0, bb, acc0);
    acc1 = MFMA(a1, bb, acc1);
  }
  float* P = ws + WS_P5 + ((size_t)ksplit * 1024 + n) * 68;
  *(f32x4*)(P + m0 + lk * 4) = acc0;
  *(f32x4*)(P + m0 + 16 + lk * 4) = acc1;
  sq += __shfl_xor(sq, 16);
  sq += __shfl_xor(sq, 32);
  if (w < 2 && l < 16) P[64] = sq;
}

// ---- K8: reduce P5 + cosnorm epilogue -> logits (XN2P now [128][64]) ----
__global__ __launch_bounds__(256) void k8(float* __restrict__ out,
                                          const float* __restrict__ ws) {
  __shared__ float tile[64][65];
  __shared__ float nr[64];
  int blk = blockIdx.x, t = threadIdx.x, l = t & 63, w = t >> 6;
  int c0 = blk * 64;
  const size_t KS = (size_t)1024 * 68;
  if (t < 64) {
    float s = 0.f;
    for (int i = 0; i < 128; ++i) s += ws[WS_XN2P + i * 64 + t];
    nr[t] = sqrtf(fmaxf(s, 0.f));
  }
  __syncthreads();
  for (int cl = w; cl < 64; cl += 4) {
    int c = c0 + cl;
    const float* P = ws + WS_P5 + (size_t)c * 68;
    float v = P[l] + P[KS + l] + P[2*KS + l] + P[3*KS + l];
    float w2 = P[64] + P[KS + 64] + P[2*KS + 64] + P[3*KS + 64];
    tile[cl][l] = 16.0f * v * rsqrtf(fmaxf(w2, 1e-30f)) / (1.0f + nr[l]);
  }
  __syncthreads();
  for (int r = 0; r < 16; ++r) {
    int b = w * 16 + r;
    int c = c0 + l;
    if (c < 1000) out[(size_t)b * 1000 + c] = tile[l][b];
  }
}

extern "C" void kernel_launch(void* const* d_in, const int* in_sizes, int n_in,
                              void* d_out, int out_size, void* d_ws, size_t ws_size,
                              hipStream_t stream) {
  const float* x       = (const float*)d_in[0];
  const float* centers = (const float*)d_in[2];
  const float* fcw     = (const float*)d_in[4];
  const float* fcb     = (const float*)d_in[5];
  const float* fc1w    = (const float*)d_in[6];
  const float* fc1b    = (const float*)d_in[7];
  const float* cosw    = (const float*)d_in[8];
  float* out = (float*)d_out;
  float* ws  = (float*)d_ws;

  hipLaunchKernelGGL(k1,  dim3(64),   dim3(256), 0, stream, x, out, ws);
  hipLaunchKernelGGL(k2,  dim3(1024), dim3(256), 0, stream, centers, fc1w, fcw, ws);
  hipLaunchKernelGGL(k3,  dim3(64),   dim3(256), 0, stream, fc1b, fcb, ws);
  hipLaunchKernelGGL(k4,  dim3(16),   dim3(256), 0, stream, ws);
  hipLaunchKernelGGL(kde, dim3(256),  dim3(256), 0, stream, centers, x, out, ws);
  hipLaunchKernelGGL(k7,  dim3(128),  dim3(256), 0, stream, cosw, ws);
  hipLaunchKernelGGL(k8,  dim3(16),   dim3(256), 0, stream, out, ws);
}

// Round 10
// 76.239 us; speedup vs baseline: 10.9810x; 1.0245x over previous
//
#include <hip/hip_runtime.h>
#include <hip/hip_bf16.h>
#include <math.h>

typedef __attribute__((ext_vector_type(8))) short short8;
typedef __attribute__((ext_vector_type(4))) float f32x4;

#define MFMA(a, b, c) __builtin_amdgcn_mfma_f32_16x16x32_bf16(a, b, c, 0, 0, 0)

// ws layout (float offsets), ~11.2 MB
enum : int {
  WS_XB   = 0,        // [64][2048] bf16 (ushort view)       65536
  WS_X2   = 65536,    // [64] f32 row sumsq of x                64
  WS_D2MIN= 65600,    // [64] uint bits                         64
  WS_P123 = 65728,    // [8][4096][68] f32 (+[64]=col sumsq) 2228224
  WS_SPART= 2293952,  // [16][64] f32 row-sum partials of E    1024
  WS_PROB = 2359488,  // [64][1024] bf16 (E, unnormalized)    32768
  WS_SEL  = 2392256,  // [64][2048] bf16                      65536
  WS_XNB  = 2457792,  // [64][2048] bf16  (y = x + fast)      65536
  WS_XN2P = 2523328,  // [128][64] f32 partials ||y||^2        8192
  WS_P5   = 2531520,  // [4][1024][68] f32 (+[64]=col sumsq) 278528 -> 2810048
};

__device__ inline short bfs(float f) {
  __hip_bfloat16 h = __float2bfloat16(f);
  return __builtin_bit_cast(short, h);
}
__device__ inline float bf2f(unsigned short u) {
  return __uint_as_float((unsigned)u << 16);
}

// ---- K1: x -> bf16, x row sumsq, slow_feature out, d2min init ----
__global__ __launch_bounds__(256) void k1(const float* __restrict__ x,
                                          float* __restrict__ out,
                                          float* __restrict__ ws) {
  __shared__ float red[4];
  int b = blockIdx.x, t = threadIdx.x;
  int l = t & 63, w = t >> 6;
  const float* xr = x + (size_t)b * 2048 + t * 8;
  float4 f0 = *(const float4*)(xr);
  float4 f1 = *(const float4*)(xr + 4);
  short8 h;
  h[0] = bfs(f0.x); h[1] = bfs(f0.y); h[2] = bfs(f0.z); h[3] = bfs(f0.w);
  h[4] = bfs(f1.x); h[5] = bfs(f1.y); h[6] = bfs(f1.z); h[7] = bfs(f1.w);
  *(short8*)((unsigned short*)(ws + WS_XB) + (size_t)b * 2048 + t * 8) = h;
  *(float4*)(out + 64000 + (size_t)b * 2048 + t * 8) = f0;
  *(float4*)(out + 64000 + (size_t)b * 2048 + t * 8 + 4) = f1;
  float s = f0.x*f0.x + f0.y*f0.y + f0.z*f0.z + f0.w*f0.w
          + f1.x*f1.x + f1.y*f1.y + f1.z*f1.z + f1.w*f1.w;
#pragma unroll
  for (int o = 32; o; o >>= 1) s += __shfl_xor(s, o);
  if (l == 0) red[w] = s;
  __syncthreads();
  if (t == 0) ws[WS_X2 + b] = red[0] + red[1] + red[2] + red[3];
  if (b == 0 && t < 64) ((unsigned*)(ws + WS_D2MIN))[t] = 0x7f800000u;  // +inf
}

// ---- K2: G123 = x @ [centers; fc1w; fcw]^T, split-K=8, FULL unroll ----
__global__ __launch_bounds__(256) void k2(const float* __restrict__ centers,
                                          const float* __restrict__ fc1w,
                                          const float* __restrict__ fcw,
                                          float* __restrict__ ws) {
  int blk = blockIdx.x, t = threadIdx.x;
  int w = t >> 6, l = t & 63;
  int colblk = blk & 127, ksplit = blk >> 7;   // 0..127 x 0..7
  int ln = l & 15, lk = l >> 4;
  int n = colblk * 32 + (w & 1) * 16 + ln;     // 0..4095
  int m0 = (w >> 1) * 32;
  int k0 = ksplit * 256;
  const float* brow;
  if (n < 1024)      brow = centers + (size_t)min(n, 999) * 2048;
  else if (n < 2048) brow = fc1w + (size_t)min(n - 1024, 999) * 2048;
  else               brow = fcw + (size_t)(n - 2048) * 2048;
  const float* bptr = brow + k0 + lk * 8;
  const unsigned short* aptr =
      (const unsigned short*)(ws + WS_XB) + (size_t)(m0 + ln) * 2048 + k0 + lk * 8;
  f32x4 acc0 = {0.f, 0.f, 0.f, 0.f}, acc1 = {0.f, 0.f, 0.f, 0.f};
  float sq = 0.f;
#pragma unroll
  for (int ks = 0; ks < 8; ++ks) {
    short8 a0 = *(const short8*)(aptr + ks * 32);
    short8 a1 = *(const short8*)(aptr + 16 * 2048 + ks * 32);
    float4 f0 = *(const float4*)(bptr + ks * 32);
    float4 f1 = *(const float4*)(bptr + ks * 32 + 4);
    sq += f0.x*f0.x + f0.y*f0.y + f0.z*f0.z + f0.w*f0.w
        + f1.x*f1.x + f1.y*f1.y + f1.z*f1.z + f1.w*f1.w;
    short8 bb;
    bb[0] = bfs(f0.x); bb[1] = bfs(f0.y); bb[2] = bfs(f0.z); bb[3] = bfs(f0.w);
    bb[4] = bfs(f1.x); bb[5] = bfs(f1.y); bb[6] = bfs(f1.z); bb[7] = bfs(f1.w);
    acc0 = MFMA(a0, bb, acc0);
    acc1 = MFMA(a1, bb, acc1);
  }
  float* P = ws + WS_P123 + ((size_t)ksplit * 4096 + n) * 68;
  *(f32x4*)(P + m0 + lk * 4) = acc0;
  *(f32x4*)(P + m0 + 16 + lk * 4) = acc1;
  sq += __shfl_xor(sq, 16);
  sq += __shfl_xor(sq, 32);
  if (w < 2 && l < 16) P[64] = sq;   // per-col ||w||^2 partial
}

// ---- K3: reduce P123 (8 splits) -> d2min | E=exp(L1) bf16 + SPART | SEL ----
__global__ __launch_bounds__(256) void k3(const float* __restrict__ fc1b,
                                          const float* __restrict__ fcb,
                                          float* __restrict__ ws) {
  __shared__ float tile[64][65];
  __shared__ float red[4][64];
  int blk = blockIdx.x, t = threadIdx.x;
  int l = t & 63, w = t >> 6;
  int n0 = blk * 64;
  const size_t KS = (size_t)4096 * 68;
  if (n0 < 1024) {
    float x2 = ws[WS_X2 + l];
    float tmin = 3.0e38f;
    for (int nl = w; nl < 64; nl += 4) {
      int n = n0 + nl;
      if (n < 1000) {
        const float* P = ws + WS_P123 + (size_t)n * 68;
        float v = 0.f, c2 = 0.f;
#pragma unroll
        for (int j = 0; j < 8; ++j) {
          v  += P[(size_t)j * KS + l];
          c2 += P[(size_t)j * KS + 64];
        }
        tmin = fminf(tmin, fmaxf(x2 - 2.f * v + c2, 0.f));
      }
    }
    red[w][l] = tmin;
    __syncthreads();
    if (t < 64) {
      float m = fminf(fminf(red[0][t], red[1][t]), fminf(red[2][t], red[3][t]));
      atomicMin((unsigned*)(ws + WS_D2MIN) + t, __float_as_uint(m));
    }
  } else if (n0 < 2048) {
    int c0 = n0 - 1024;
    for (int nl = w; nl < 64; nl += 4) {
      int c = c0 + nl;
      const float* P = ws + WS_P123 + (size_t)(n0 + nl) * 68;
      float v = 0.f;
#pragma unroll
      for (int j = 0; j < 8; ++j) v += P[(size_t)j * KS + l];
      tile[nl][l] = (c < 1000) ? __expf(v + fc1b[c]) : 0.f;  // E, no max-sub
    }
    __syncthreads();
    unsigned short* pb = (unsigned short*)(ws + WS_PROB);
    for (int r = 0; r < 16; ++r) {
      int m = w * 16 + r;
      pb[(size_t)m * 1024 + c0 + l] = (unsigned short)bfs(tile[l][m]);
    }
    if (t < 64) {                       // per-block row-sum of E
      float s = 0.f;
#pragma unroll
      for (int nl = 0; nl < 64; ++nl) s += tile[nl][t];
      ws[WS_SPART + (blk - 16) * 64 + t] = s;
    }
  } else {
    int d0 = n0 - 2048;
    for (int nl = w; nl < 64; nl += 4) {
      const float* P = ws + WS_P123 + (size_t)(n0 + nl) * 68;
      float v = 0.f;
#pragma unroll
      for (int j = 0; j < 8; ++j) v += P[(size_t)j * KS + l];
      tile[nl][l] = tanhf(v + fcb[d0 + nl]);
    }
    __syncthreads();
    unsigned short* sel = (unsigned short*)(ws + WS_SEL);
    for (int r = 0; r < 16; ++r) {
      int m = w * 16 + r;
      sel[(size_t)m * 2048 + d0 + l] = (unsigned short)bfs(tile[l][m]);
    }
  }
}

// ---- KDE: G4 = E @ centers (intra-block K-split) / s + fused y epilogue ----
// 256 blocks = 128 col-groups (16 d) x 2 m-halves (32 b)
__global__ __launch_bounds__(256) void kde(const float* __restrict__ centers,
                                           const float* __restrict__ x,
                                           float* __restrict__ out,
                                           float* __restrict__ ws) {
  __shared__ f32x4 sacc[4][2][64];   // 8 KB
  __shared__ float sinv[64];
  int blk = blockIdx.x, t = threadIdx.x;
  int w = t >> 6, l = t & 63;
  int cs = blk >> 1, mh = blk & 1;
  int d0 = cs * 16, m0 = mh * 32;
  int ln = l & 15, lk = l >> 4;
  int k0 = w * 256;
  if (t < 64) {
    float s = 0.f;
#pragma unroll
    for (int i = 0; i < 16; ++i) s += ws[WS_SPART + i * 64 + t];
    sinv[t] = 1.0f / s;
  }
  const unsigned short* aptr =
      (const unsigned short*)(ws + WS_PROB) + (size_t)(m0 + ln) * 1024 + k0 + lk * 8;
  f32x4 acc0 = {0.f, 0.f, 0.f, 0.f}, acc1 = {0.f, 0.f, 0.f, 0.f};
  for (int ks = 0; ks < 8; ++ks) {
    short8 a0 = *(const short8*)(aptr + ks * 32);
    short8 a1 = *(const short8*)(aptr + 16 * 1024 + ks * 32);
    int kbase = k0 + ks * 32 + lk * 8;
    short8 bb;
#pragma unroll
    for (int j = 0; j < 8; ++j) {
      int kc = min(kbase + j, 999);
      bb[j] = bfs(centers[(size_t)kc * 2048 + d0 + ln]);
    }
    acc0 = MFMA(a0, bb, acc0);
    acc1 = MFMA(a1, bb, acc1);
  }
  sacc[w][0][l] = acc0;
  sacc[w][1][l] = acc1;
  __syncthreads();
  if (w == 0) {
    f32x4 r0 = sacc[0][0][l], r1 = sacc[0][1][l];
#pragma unroll
    for (int i = 1; i < 4; ++i) {
      f32x4 u0 = sacc[i][0][l], u1 = sacc[i][1][l];
      r0.x += u0.x; r0.y += u0.y; r0.z += u0.z; r0.w += u0.w;
      r1.x += u1.x; r1.y += u1.y; r1.z += u1.z; r1.w += u1.w;
    }
    const unsigned short* sel = (const unsigned short*)(ws + WS_SEL);
    unsigned short* xnb = (unsigned short*)(ws + WS_XNB);
    float rr[8] = {r0.x, r0.y, r0.z, r0.w, r1.x, r1.y, r1.z, r1.w};
#pragma unroll
    for (int q = 0; q < 8; ++q) {
      int b = m0 + (q >> 2) * 16 + lk * 4 + (q & 3);
      int d = d0 + ln;
      float cc = rr[q] * sinv[b];            // centers_cur = (E@centers)/s
      float sv = bf2f(sel[(size_t)b * 2048 + d]);
      float xv = x[(size_t)b * 2048 + d];
      float fast = sv * cc;
      out[195072 + (size_t)b * 2048 + d] = fast;
      float yv = xv + fast;                  // y (conf applied in k8)
      xnb[(size_t)b * 2048 + d] = (unsigned short)bfs(yv);
      float sq = yv * yv;
      sq += __shfl_xor(sq, 1);
      sq += __shfl_xor(sq, 2);
      sq += __shfl_xor(sq, 4);
      sq += __shfl_xor(sq, 8);
      if (ln == 0) ws[WS_XN2P + cs * 64 + b] = sq;
    }
  }
}

// ---- K7: G5 = y @ cosw^T + ||w||^2 partials; grid 128 = 32 x 4 ----
__global__ __launch_bounds__(256) void k7(const float* __restrict__ cosw,
                                          float* __restrict__ ws) {
  int blk = blockIdx.x, t = threadIdx.x;
  int w = t >> 6, l = t & 63;
  int colblk = blk & 31, ksplit = blk >> 5;
  int ln = l & 15, lk = l >> 4;
  int n = colblk * 32 + (w & 1) * 16 + ln;   // 0..1023
  int m0 = (w >> 1) * 32;
  int k0 = ksplit * 512;
  const float* bptr = cosw + (size_t)min(n, 999) * 2048 + k0 + lk * 8;
  const unsigned short* aptr =
      (const unsigned short*)(ws + WS_XNB) + (size_t)(m0 + ln) * 2048 + k0 + lk * 8;
  f32x4 acc0 = {0.f, 0.f, 0.f, 0.f}, acc1 = {0.f, 0.f, 0.f, 0.f};
  float sq = 0.f;
#pragma unroll 4
  for (int ks = 0; ks < 16; ++ks) {
    short8 a0 = *(const short8*)(aptr + ks * 32);
    short8 a1 = *(const short8*)(aptr + 16 * 2048 + ks * 32);
    float4 f0 = *(const float4*)(bptr + ks * 32);
    float4 f1 = *(const float4*)(bptr + ks * 32 + 4);
    sq += f0.x*f0.x + f0.y*f0.y + f0.z*f0.z + f0.w*f0.w
        + f1.x*f1.x + f1.y*f1.y + f1.z*f1.z + f1.w*f1.w;
    short8 bb;
    bb[0] = bfs(f0.x); bb[1] = bfs(f0.y); bb[2] = bfs(f0.z); bb[3] = bfs(f0.w);
    bb[4] = bfs(f1.x); bb[5] = bfs(f1.y); bb[6] = bfs(f1.z); bb[7] = bfs(f1.w);
    acc0 = MFMA(a0, bb, acc0);
    acc1 = MFMA(a1, bb, acc1);
  }
  float* P = ws + WS_P5 + ((size_t)ksplit * 1024 + n) * 68;
  *(f32x4*)(P + m0 + lk * 4) = acc0;
  *(f32x4*)(P + m0 + 16 + lk * 4) = acc1;
  sq += __shfl_xor(sq, 16);
  sq += __shfl_xor(sq, 32);
  if (w < 2 && l < 16) P[64] = sq;
}

// ---- K8: reduce P5 + conf-aware cosnorm epilogue -> logits ----
__global__ __launch_bounds__(256) void k8(float* __restrict__ out,
                                          const float* __restrict__ ws) {
  __shared__ float tile[64][65];
  __shared__ float scale[64];
  int blk = blockIdx.x, t = threadIdx.x, l = t & 63, w = t >> 6;
  int c0 = blk * 64;
  const size_t KS = (size_t)1024 * 68;
  if (t < 64) {
    float s = 0.f;
    for (int i = 0; i < 128; ++i) s += ws[WS_XN2P + i * 64 + t];
    float ny = sqrtf(fmaxf(s, 0.f));                       // ||y||
    float d2 = __uint_as_float(((const unsigned*)(ws + WS_D2MIN))[t]);
    float cf = 10.0f * rsqrtf(fmaxf(d2, 1e-20f));          // conf
    scale[t] = 16.0f * cf / (1.0f + cf * ny);
  }
  __syncthreads();
  for (int cl = w; cl < 64; cl += 4) {
    int c = c0 + cl;
    const float* P = ws + WS_P5 + (size_t)c * 68;
    float v = P[l] + P[KS + l] + P[2*KS + l] + P[3*KS + l];
    float w2 = P[64] + P[KS + 64] + P[2*KS + 64] + P[3*KS + 64];
    tile[cl][l] = v * rsqrtf(fmaxf(w2, 1e-30f)) * scale[l];
  }
  __syncthreads();
  for (int r = 0; r < 16; ++r) {
    int b = w * 16 + r;
    int c = c0 + l;
    if (c < 1000) out[(size_t)b * 1000 + c] = tile[l][b];
  }
}

extern "C" void kernel_launch(void* const* d_in, const int* in_sizes, int n_in,
                              void* d_out, int out_size, void* d_ws, size_t ws_size,
                              hipStream_t stream) {
  const float* x       = (const float*)d_in[0];
  const float* centers = (const float*)d_in[2];
  const float* fcw     = (const float*)d_in[4];
  const float* fcb     = (const float*)d_in[5];
  const float* fc1w    = (const float*)d_in[6];
  const float* fc1b    = (const float*)d_in[7];
  const float* cosw    = (const float*)d_in[8];
  float* out = (float*)d_out;
  float* ws  = (float*)d_ws;

  hipLaunchKernelGGL(k1,  dim3(64),   dim3(256), 0, stream, x, out, ws);
  hipLaunchKernelGGL(k2,  dim3(1024), dim3(256), 0, stream, centers, fc1w, fcw, ws);
  hipLaunchKernelGGL(k3,  dim3(64),   dim3(256), 0, stream, fc1b, fcb, ws);
  hipLaunchKernelGGL(kde, dim3(256),  dim3(256), 0, stream, centers, x, out, ws);
  hipLaunchKernelGGL(k7,  dim3(128),  dim3(256), 0, stream, cosw, ws);
  hipLaunchKernelGGL(k8,  dim3(16),   dim3(256), 0, stream, out, ws);
}

// Round 11
// 72.591 us; speedup vs baseline: 11.5328x; 1.0503x over previous
//
#include <hip/hip_runtime.h>
#include <hip/hip_bf16.h>
#include <math.h>

typedef __attribute__((ext_vector_type(8))) short short8;
typedef __attribute__((ext_vector_type(4))) float f32x4;

#define MFMA(a, b, c) __builtin_amdgcn_mfma_f32_16x16x32_bf16(a, b, c, 0, 0, 0)

// ws layout (float offsets), ~11.2 MB
enum : int {
  WS_XB   = 0,        // [64][2048] bf16 (ushort view)       65536
  WS_X2   = 65536,    // [64] f32 row sumsq of x                64
  WS_D2MIN= 65600,    // [64] uint bits                         64
  WS_P123 = 65728,    // [8][4096][68] f32 (+[64]=col sumsq) 2228224
  WS_SPART= 2293952,  // [16][64] f32 row-sum partials of E    1024
  WS_PROB = 2359488,  // [64][1024] bf16 (E, unnormalized)    32768
  WS_SEL  = 2392256,  // [64][2048] bf16                      65536
  WS_XNB  = 2457792,  // [64][2048] bf16  (y = x + fast)      65536
  WS_XN2P = 2523328,  // [128][64] f32 partials ||y||^2        8192
  WS_P5   = 2531520,  // [4][1024][68] f32 (+[64]=col sumsq) 278528 -> 2810048
};

__device__ inline short bfs(float f) {
  __hip_bfloat16 h = __float2bfloat16(f);
  return __builtin_bit_cast(short, h);
}
__device__ inline float bf2f(unsigned short u) {
  return __uint_as_float((unsigned)u << 16);
}

// async global->LDS, 16B per lane; LDS dest = wave-uniform base + lane*16
__device__ inline void gload16(const float* g, float* lds) {
  __builtin_amdgcn_global_load_lds(
      (const __attribute__((address_space(1))) unsigned int*)g,
      (__attribute__((address_space(3))) unsigned int*)lds, 16, 0, 0);
}

// ---- K1: x -> bf16, x row sumsq, slow_feature out, d2min init ----
__global__ __launch_bounds__(256) void k1(const float* __restrict__ x,
                                          float* __restrict__ out,
                                          float* __restrict__ ws) {
  __shared__ float red[4];
  int b = blockIdx.x, t = threadIdx.x;
  int l = t & 63, w = t >> 6;
  const float* xr = x + (size_t)b * 2048 + t * 8;
  float4 f0 = *(const float4*)(xr);
  float4 f1 = *(const float4*)(xr + 4);
  short8 h;
  h[0] = bfs(f0.x); h[1] = bfs(f0.y); h[2] = bfs(f0.z); h[3] = bfs(f0.w);
  h[4] = bfs(f1.x); h[5] = bfs(f1.y); h[6] = bfs(f1.z); h[7] = bfs(f1.w);
  *(short8*)((unsigned short*)(ws + WS_XB) + (size_t)b * 2048 + t * 8) = h;
  *(float4*)(out + 64000 + (size_t)b * 2048 + t * 8) = f0;
  *(float4*)(out + 64000 + (size_t)b * 2048 + t * 8 + 4) = f1;
  float s = f0.x*f0.x + f0.y*f0.y + f0.z*f0.z + f0.w*f0.w
          + f1.x*f1.x + f1.y*f1.y + f1.z*f1.z + f1.w*f1.w;
#pragma unroll
  for (int o = 32; o; o >>= 1) s += __shfl_xor(s, o);
  if (l == 0) red[w] = s;
  __syncthreads();
  if (t == 0) ws[WS_X2 + b] = red[0] + red[1] + red[2] + red[3];
  if (b == 0 && t < 64) ((unsigned*)(ws + WS_D2MIN))[t] = 0x7f800000u;  // +inf
}

// ---- K2: G123 via global_load_lds-staged W tiles (32 KB/block) ----
// grid 1024 = 128 colblk x 8 ksplit; LDS WT[32][260] f32
__global__ __launch_bounds__(256) void k2(const float* __restrict__ centers,
                                          const float* __restrict__ fc1w,
                                          const float* __restrict__ fcw,
                                          float* __restrict__ ws) {
  __shared__ float WT[32][260];   // 33.3 KB, row stride 260 (16B-aligned, bank-spread)
  int blk = blockIdx.x, t = threadIdx.x;
  int w = t >> 6, l = t & 63;
  int colblk = blk & 127, ksplit = blk >> 7;   // 0..127 x 0..7
  int ln = l & 15, lk = l >> 4;
  int nbase = colblk * 32;
  int k0 = ksplit * 256;

  // stage: wave w loads rows w*8..w*8+7, each row = 1 KB fully-coalesced async
#pragma unroll
  for (int i = 0; i < 8; ++i) {
    int r = w * 8 + i;
    int n = nbase + r;
    const float* brow;
    if (n < 1024)      brow = centers + (size_t)min(n, 999) * 2048;
    else if (n < 2048) brow = fc1w + (size_t)min(n - 1024, 999) * 2048;
    else               brow = fcw + (size_t)(n - 2048) * 2048;
    gload16(brow + k0 + l * 4, &WT[r][0]);
  }
  __syncthreads();   // drains vmcnt (incl. global_load_lds) before LDS reads

  int n = nbase + (w & 1) * 16 + ln;   // this lane's output column
  int m0 = (w >> 1) * 32;
  const unsigned short* aptr =
      (const unsigned short*)(ws + WS_XB) + (size_t)(m0 + ln) * 2048 + k0 + lk * 8;
  const float* wrow = &WT[(w & 1) * 16 + ln][lk * 8];
  f32x4 acc0 = {0.f, 0.f, 0.f, 0.f}, acc1 = {0.f, 0.f, 0.f, 0.f};
  float sq = 0.f;
#pragma unroll
  for (int ks = 0; ks < 8; ++ks) {
    short8 a0 = *(const short8*)(aptr + ks * 32);
    short8 a1 = *(const short8*)(aptr + 16 * 2048 + ks * 32);
    float4 f0 = *(const float4*)(wrow + ks * 32);
    float4 f1 = *(const float4*)(wrow + ks * 32 + 4);
    sq += f0.x*f0.x + f0.y*f0.y + f0.z*f0.z + f0.w*f0.w
        + f1.x*f1.x + f1.y*f1.y + f1.z*f1.z + f1.w*f1.w;
    short8 bb;
    bb[0] = bfs(f0.x); bb[1] = bfs(f0.y); bb[2] = bfs(f0.z); bb[3] = bfs(f0.w);
    bb[4] = bfs(f1.x); bb[5] = bfs(f1.y); bb[6] = bfs(f1.z); bb[7] = bfs(f1.w);
    acc0 = MFMA(a0, bb, acc0);
    acc1 = MFMA(a1, bb, acc1);
  }
  float* P = ws + WS_P123 + ((size_t)ksplit * 4096 + n) * 68;
  *(f32x4*)(P + m0 + lk * 4) = acc0;
  *(f32x4*)(P + m0 + 16 + lk * 4) = acc1;
  sq += __shfl_xor(sq, 16);
  sq += __shfl_xor(sq, 32);
  if (w < 2 && l < 16) P[64] = sq;   // per-col ||w||^2 partial
}

// ---- K3: reduce P123 (8 splits) -> d2min | E=exp(L1) bf16 + SPART | SEL ----
__global__ __launch_bounds__(256) void k3(const float* __restrict__ fc1b,
                                          const float* __restrict__ fcb,
                                          float* __restrict__ ws) {
  __shared__ float tile[64][65];
  __shared__ float red[4][64];
  int blk = blockIdx.x, t = threadIdx.x;
  int l = t & 63, w = t >> 6;
  int n0 = blk * 64;
  const size_t KS = (size_t)4096 * 68;
  if (n0 < 1024) {
    float x2 = ws[WS_X2 + l];
    float tmin = 3.0e38f;
    for (int nl = w; nl < 64; nl += 4) {
      int n = n0 + nl;
      if (n < 1000) {
        const float* P = ws + WS_P123 + (size_t)n * 68;
        float v = 0.f, c2 = 0.f;
#pragma unroll
        for (int j = 0; j < 8; ++j) {
          v  += P[(size_t)j * KS + l];
          c2 += P[(size_t)j * KS + 64];
        }
        tmin = fminf(tmin, fmaxf(x2 - 2.f * v + c2, 0.f));
      }
    }
    red[w][l] = tmin;
    __syncthreads();
    if (t < 64) {
      float m = fminf(fminf(red[0][t], red[1][t]), fminf(red[2][t], red[3][t]));
      atomicMin((unsigned*)(ws + WS_D2MIN) + t, __float_as_uint(m));
    }
  } else if (n0 < 2048) {
    int c0 = n0 - 1024;
    for (int nl = w; nl < 64; nl += 4) {
      int c = c0 + nl;
      const float* P = ws + WS_P123 + (size_t)(n0 + nl) * 68;
      float v = 0.f;
#pragma unroll
      for (int j = 0; j < 8; ++j) v += P[(size_t)j * KS + l];
      tile[nl][l] = (c < 1000) ? __expf(v + fc1b[c]) : 0.f;  // E, no max-sub
    }
    __syncthreads();
    unsigned short* pb = (unsigned short*)(ws + WS_PROB);
    for (int r = 0; r < 16; ++r) {
      int m = w * 16 + r;
      pb[(size_t)m * 1024 + c0 + l] = (unsigned short)bfs(tile[l][m]);
    }
    if (t < 64) {                       // per-block row-sum of E
      float s = 0.f;
#pragma unroll
      for (int nl = 0; nl < 64; ++nl) s += tile[nl][t];
      ws[WS_SPART + (blk - 16) * 64 + t] = s;
    }
  } else {
    int d0 = n0 - 2048;
    for (int nl = w; nl < 64; nl += 4) {
      const float* P = ws + WS_P123 + (size_t)(n0 + nl) * 68;
      float v = 0.f;
#pragma unroll
      for (int j = 0; j < 8; ++j) v += P[(size_t)j * KS + l];
      tile[nl][l] = tanhf(v + fcb[d0 + nl]);
    }
    __syncthreads();
    unsigned short* sel = (unsigned short*)(ws + WS_SEL);
    for (int r = 0; r < 16; ++r) {
      int m = w * 16 + r;
      sel[(size_t)m * 2048 + d0 + l] = (unsigned short)bfs(tile[l][m]);
    }
  }
}

// ---- KDE: G4 = E @ centers (intra-block K-split) / s + fused y epilogue ----
// 256 blocks = 128 col-groups (16 d) x 2 m-halves (32 b)
__global__ __launch_bounds__(256) void kde(const float* __restrict__ centers,
                                           const float* __restrict__ x,
                                           float* __restrict__ out,
                                           float* __restrict__ ws) {
  __shared__ f32x4 sacc[4][2][64];   // 8 KB
  __shared__ float sinv[64];
  int blk = blockIdx.x, t = threadIdx.x;
  int w = t >> 6, l = t & 63;
  int cs = blk >> 1, mh = blk & 1;
  int d0 = cs * 16, m0 = mh * 32;
  int ln = l & 15, lk = l >> 4;
  int k0 = w * 256;
  if (t < 64) {
    float s = 0.f;
#pragma unroll
    for (int i = 0; i < 16; ++i) s += ws[WS_SPART + i * 64 + t];
    sinv[t] = 1.0f / s;
  }
  const unsigned short* aptr =
      (const unsigned short*)(ws + WS_PROB) + (size_t)(m0 + ln) * 1024 + k0 + lk * 8;
  f32x4 acc0 = {0.f, 0.f, 0.f, 0.f}, acc1 = {0.f, 0.f, 0.f, 0.f};
  for (int ks = 0; ks < 8; ++ks) {
    short8 a0 = *(const short8*)(aptr + ks * 32);
    short8 a1 = *(const short8*)(aptr + 16 * 1024 + ks * 32);
    int kbase = k0 + ks * 32 + lk * 8;
    short8 bb;
#pragma unroll
    for (int j = 0; j < 8; ++j) {
      int kc = min(kbase + j, 999);
      bb[j] = bfs(centers[(size_t)kc * 2048 + d0 + ln]);
    }
    acc0 = MFMA(a0, bb, acc0);
    acc1 = MFMA(a1, bb, acc1);
  }
  sacc[w][0][l] = acc0;
  sacc[w][1][l] = acc1;
  __syncthreads();
  if (w == 0) {
    f32x4 r0 = sacc[0][0][l], r1 = sacc[0][1][l];
#pragma unroll
    for (int i = 1; i < 4; ++i) {
      f32x4 u0 = sacc[i][0][l], u1 = sacc[i][1][l];
      r0.x += u0.x; r0.y += u0.y; r0.z += u0.z; r0.w += u0.w;
      r1.x += u1.x; r1.y += u1.y; r1.z += u1.z; r1.w += u1.w;
    }
    const unsigned short* sel = (const unsigned short*)(ws + WS_SEL);
    unsigned short* xnb = (unsigned short*)(ws + WS_XNB);
    float rr[8] = {r0.x, r0.y, r0.z, r0.w, r1.x, r1.y, r1.z, r1.w};
#pragma unroll
    for (int q = 0; q < 8; ++q) {
      int b = m0 + (q >> 2) * 16 + lk * 4 + (q & 3);
      int d = d0 + ln;
      float cc = rr[q] * sinv[b];            // centers_cur = (E@centers)/s
      float sv = bf2f(sel[(size_t)b * 2048 + d]);
      float xv = x[(size_t)b * 2048 + d];
      float fast = sv * cc;
      out[195072 + (size_t)b * 2048 + d] = fast;
      float yv = xv + fast;                  // y (conf applied in k8)
      xnb[(size_t)b * 2048 + d] = (unsigned short)bfs(yv);
      float sq = yv * yv;
      sq += __shfl_xor(sq, 1);
      sq += __shfl_xor(sq, 2);
      sq += __shfl_xor(sq, 4);
      sq += __shfl_xor(sq, 8);
      if (ln == 0) ws[WS_XN2P + cs * 64 + b] = sq;
    }
  }
}

// ---- K7: G5 = y @ cosw^T + ||w||^2 partials; grid 128 = 32 x 4 ----
__global__ __launch_bounds__(256) void k7(const float* __restrict__ cosw,
                                          float* __restrict__ ws) {
  int blk = blockIdx.x, t = threadIdx.x;
  int w = t >> 6, l = t & 63;
  int colblk = blk & 31, ksplit = blk >> 5;
  int ln = l & 15, lk = l >> 4;
  int n = colblk * 32 + (w & 1) * 16 + ln;   // 0..1023
  int m0 = (w >> 1) * 32;
  int k0 = ksplit * 512;
  const float* bptr = cosw + (size_t)min(n, 999) * 2048 + k0 + lk * 8;
  const unsigned short* aptr =
      (const unsigned short*)(ws + WS_XNB) + (size_t)(m0 + ln) * 2048 + k0 + lk * 8;
  f32x4 acc0 = {0.f, 0.f, 0.f, 0.f}, acc1 = {0.f, 0.f, 0.f, 0.f};
  float sq = 0.f;
#pragma unroll 4
  for (int ks = 0; ks < 16; ++ks) {
    short8 a0 = *(const short8*)(aptr + ks * 32);
    short8 a1 = *(const short8*)(aptr + 16 * 2048 + ks * 32);
    float4 f0 = *(const float4*)(bptr + ks * 32);
    float4 f1 = *(const float4*)(bptr + ks * 32 + 4);
    sq += f0.x*f0.x + f0.y*f0.y + f0.z*f0.z + f0.w*f0.w
        + f1.x*f1.x + f1.y*f1.y + f1.z*f1.z + f1.w*f1.w;
    short8 bb;
    bb[0] = bfs(f0.x); bb[1] = bfs(f0.y); bb[2] = bfs(f0.z); bb[3] = bfs(f0.w);
    bb[4] = bfs(f1.x); bb[5] = bfs(f1.y); bb[6] = bfs(f1.z); bb[7] = bfs(f1.w);
    acc0 = MFMA(a0, bb, acc0);
    acc1 = MFMA(a1, bb, acc1);
  }
  float* P = ws + WS_P5 + ((size_t)ksplit * 1024 + n) * 68;
  *(f32x4*)(P + m0 + lk * 4) = acc0;
  *(f32x4*)(P + m0 + 16 + lk * 4) = acc1;
  sq += __shfl_xor(sq, 16);
  sq += __shfl_xor(sq, 32);
  if (w < 2 && l < 16) P[64] = sq;
}

// ---- K8: reduce P5 + conf-aware cosnorm epilogue -> logits ----
__global__ __launch_bounds__(256) void k8(float* __restrict__ out,
                                          const float* __restrict__ ws) {
  __shared__ float tile[64][65];
  __shared__ float scale[64];
  int blk = blockIdx.x, t = threadIdx.x, l = t & 63, w = t >> 6;
  int c0 = blk * 64;
  const size_t KS = (size_t)1024 * 68;
  if (t < 64) {
    float s = 0.f;
    for (int i = 0; i < 128; ++i) s += ws[WS_XN2P + i * 64 + t];
    float ny = sqrtf(fmaxf(s, 0.f));                       // ||y||
    float d2 = __uint_as_float(((const unsigned*)(ws + WS_D2MIN))[t]);
    float cf = 10.0f * rsqrtf(fmaxf(d2, 1e-20f));          // conf
    scale[t] = 16.0f * cf / (1.0f + cf * ny);
  }
  __syncthreads();
  for (int cl = w; cl < 64; cl += 4) {
    int c = c0 + cl;
    const float* P = ws + WS_P5 + (size_t)c * 68;
    float v = P[l] + P[KS + l] + P[2*KS + l] + P[3*KS + l];
    float w2 = P[64] + P[KS + 64] + P[2*KS + 64] + P[3*KS + 64];
    tile[cl][l] = v * rsqrtf(fmaxf(w2, 1e-30f)) * scale[l];
  }
  __syncthreads();
  for (int r = 0; r < 16; ++r) {
    int b = w * 16 + r;
    int c = c0 + l;
    if (c < 1000) out[(size_t)b * 1000 + c] = tile[l][b];
  }
}

extern "C" void kernel_launch(void* const* d_in, const int* in_sizes, int n_in,
                              void* d_out, int out_size, void* d_ws, size_t ws_size,
                              hipStream_t stream) {
  const float* x       = (const float*)d_in[0];
  const float* centers = (const float*)d_in[2];
  const float* fcw     = (const float*)d_in[4];
  const float* fcb     = (const float*)d_in[5];
  const float* fc1w    = (const float*)d_in[6];
  const float* fc1b    = (const float*)d_in[7];
  const float* cosw    = (const float*)d_in[8];
  float* out = (float*)d_out;
  float* ws  = (float*)d_ws;

  hipLaunchKernelGGL(k1,  dim3(64),   dim3(256), 0, stream, x, out, ws);
  hipLaunchKernelGGL(k2,  dim3(1024), dim3(256), 0, stream, centers, fc1w, fcw, ws);
  hipLaunchKernelGGL(k3,  dim3(64),   dim3(256), 0, stream, fc1b, fcb, ws);
  hipLaunchKernelGGL(kde, dim3(256),  dim3(256), 0, stream, centers, x, out, ws);
  hipLaunchKernelGGL(k7,  dim3(128),  dim3(256), 0, stream, cosw, ws);
  hipLaunchKernelGGL(k8,  dim3(16),   dim3(256), 0, stream, out, ws);
}

// Round 12
// 69.566 us; speedup vs baseline: 12.0343x; 1.0435x over previous
//
#include <hip/hip_runtime.h>
#include <hip/hip_bf16.h>
#include <math.h>

typedef __attribute__((ext_vector_type(8))) short short8;
typedef __attribute__((ext_vector_type(4))) float f32x4;

#define MFMA(a, b, c) __builtin_amdgcn_mfma_f32_16x16x32_bf16(a, b, c, 0, 0, 0)

// ws layout (float offsets), ~2.1 MB. Every slab fully plain-stored before read
// in a strictly earlier launch (stream-ordered). No atomics.
enum : int {
  WS_XB    = 0,        // [64][2048] bf16 (ushort view)       65536 floats
  WS_X2    = 65536,    // [64] f32 row sumsq of x                64
  WS_DMINP = 65600,    // [64][64] f32 per-block d2 col-minima 4096
  WS_SPART = 69696,    // [64][64] f32 row-sum partials of E   4096
  WS_PROB  = 73792,    // [64][1024] bf16 (E, unnormalized)   32768
  WS_SEL   = 106560,   // [64][2048] bf16                     65536
  WS_XNB   = 172096,   // [64][2048] bf16  (y = x + fast)     65536
  WS_XN2P  = 237632,   // [128][64] f32 partials ||y||^2       8192
  WS_P5    = 245824,   // [4][1024][68] f32 (+[64]=col sumsq) 278528 -> 524352
};

__device__ inline short bfs(float f) {
  __hip_bfloat16 h = __float2bfloat16(f);
  return __builtin_bit_cast(short, h);
}
__device__ inline float bf2f(unsigned short u) {
  return __uint_as_float((unsigned)u << 16);
}

// async global->LDS, 16B per lane; LDS dest = wave-uniform base + lane*16
__device__ inline void gload16(const float* g, float* lds) {
  __builtin_amdgcn_global_load_lds(
      (const __attribute__((address_space(1))) unsigned int*)g,
      (__attribute__((address_space(3))) unsigned int*)lds, 16, 0, 0);
}

// ---- K1: x -> bf16, x row sumsq, slow_feature out ----
__global__ __launch_bounds__(256) void k1(const float* __restrict__ x,
                                          float* __restrict__ out,
                                          float* __restrict__ ws) {
  __shared__ float red[4];
  int b = blockIdx.x, t = threadIdx.x;
  int l = t & 63, w = t >> 6;
  const float* xr = x + (size_t)b * 2048 + t * 8;
  float4 f0 = *(const float4*)(xr);
  float4 f1 = *(const float4*)(xr + 4);
  short8 h;
  h[0] = bfs(f0.x); h[1] = bfs(f0.y); h[2] = bfs(f0.z); h[3] = bfs(f0.w);
  h[4] = bfs(f1.x); h[5] = bfs(f1.y); h[6] = bfs(f1.z); h[7] = bfs(f1.w);
  *(short8*)((unsigned short*)(ws + WS_XB) + (size_t)b * 2048 + t * 8) = h;
  *(float4*)(out + 64000 + (size_t)b * 2048 + t * 8) = f0;
  *(float4*)(out + 64000 + (size_t)b * 2048 + t * 8 + 4) = f1;
  float s = f0.x*f0.x + f0.y*f0.y + f0.z*f0.z + f0.w*f0.w
          + f1.x*f1.x + f1.y*f1.y + f1.z*f1.z + f1.w*f1.w;
#pragma unroll
  for (int o = 32; o; o >>= 1) s += __shfl_xor(s, o);
  if (l == 0) red[w] = s;
  __syncthreads();
  if (t == 0) ws[WS_X2 + b] = red[0] + red[1] + red[2] + red[3];
}

// ---- K2: G123 full-K in-block. 256 blocks x 16 cols; W tile staged whole
// (16 rows x 2048 f32 = 128 KB LDS) via global_load_lds; wave w owns m-tile w.
// Epilogue emits DMINP / PROB+SPART / SEL directly (no partial slab).
__global__ __launch_bounds__(256) void k2(const float* __restrict__ centers,
                                          const float* __restrict__ fc1w,
                                          const float* __restrict__ fcw,
                                          const float* __restrict__ fc1b,
                                          const float* __restrict__ fcb,
                                          float* __restrict__ ws) {
  __shared__ float WT[16][2052];   // 131.3 KB; +4 pad breaks 2048-stride banks
  int blk = blockIdx.x, t = threadIdx.x;
  int w = t >> 6, l = t & 63;
  int ln = l & 15, lk = l >> 4;
  int n0 = blk * 16;

  // stage: wave w loads WT rows 4w..4w+3; each row 2048 f32 = 8 x 1KB async
  for (int r = 0; r < 4; ++r) {
    int row = w * 4 + r;
    int n = n0 + row;
    const float* brow;
    if (n < 1024)      brow = centers + (size_t)min(n, 999) * 2048;
    else if (n < 2048) brow = fc1w + (size_t)min(n - 1024, 999) * 2048;
    else               brow = fcw + (size_t)(n - 2048) * 2048;
#pragma unroll
    for (int c = 0; c < 8; ++c)
      gload16(brow + c * 256 + l * 4, &WT[row][c * 256]);
  }
  __syncthreads();   // drains vmcnt -> tile resident

  int m0 = w * 16;
  const unsigned short* aptr =
      (const unsigned short*)(ws + WS_XB) + (size_t)(m0 + ln) * 2048 + lk * 8;
  const float* wrow = &WT[ln][lk * 8];
  f32x4 acc = {0.f, 0.f, 0.f, 0.f};
  bool cen = (n0 < 1024);
  float sq = 0.f;
#pragma unroll 8
  for (int ks = 0; ks < 64; ++ks) {
    short8 a0 = *(const short8*)(aptr + ks * 32);
    float4 f0 = *(const float4*)(wrow + ks * 32);
    float4 f1 = *(const float4*)(wrow + ks * 32 + 4);
    if (cen)
      sq += f0.x*f0.x + f0.y*f0.y + f0.z*f0.z + f0.w*f0.w
          + f1.x*f1.x + f1.y*f1.y + f1.z*f1.z + f1.w*f1.w;
    short8 bb;
    bb[0] = bfs(f0.x); bb[1] = bfs(f0.y); bb[2] = bfs(f0.z); bb[3] = bfs(f0.w);
    bb[4] = bfs(f1.x); bb[5] = bfs(f1.y); bb[6] = bfs(f1.z); bb[7] = bfs(f1.w);
    acc = MFMA(a0, bb, acc);
  }

  // C/D mapping (validated): value acc[j] = dot(x[m0+lk*4+j], W[n0+ln])
  if (cen) {
    sq += __shfl_xor(sq, 16);
    sq += __shfl_xor(sq, 32);          // c2 for col n0+ln
    int colv = n0 + ln;
#pragma unroll
    for (int j = 0; j < 4; ++j) {
      int m = m0 + lk * 4 + j;
      float d2 = (colv < 1000)
          ? fmaxf(ws[WS_X2 + m] - 2.f * acc[j] + sq, 0.f) : 3.0e38f;
      d2 = fminf(d2, __shfl_xor(d2, 1));
      d2 = fminf(d2, __shfl_xor(d2, 2));
      d2 = fminf(d2, __shfl_xor(d2, 4));
      d2 = fminf(d2, __shfl_xor(d2, 8));
      if (ln == 0) ws[WS_DMINP + blk * 64 + m] = d2;
    }
  } else if (n0 < 2048) {
    int c = n0 - 1024 + ln;
    unsigned short* pb = (unsigned short*)(ws + WS_PROB);
#pragma unroll
    for (int j = 0; j < 4; ++j) {
      int m = m0 + lk * 4 + j;
      float e = (c < 1000) ? __expf(acc[j] + fc1b[c]) : 0.f;
      pb[(size_t)m * 1024 + c] = (unsigned short)bfs(e);
      float s = e;
      s += __shfl_xor(s, 1);
      s += __shfl_xor(s, 2);
      s += __shfl_xor(s, 4);
      s += __shfl_xor(s, 8);
      if (ln == 0) ws[WS_SPART + (blk - 64) * 64 + m] = s;
    }
  } else {
    int d = n0 - 2048 + ln;
    unsigned short* sel = (unsigned short*)(ws + WS_SEL);
#pragma unroll
    for (int j = 0; j < 4; ++j) {
      int m = m0 + lk * 4 + j;
      float sv = tanhf(acc[j] + fcb[d]);
      sel[(size_t)m * 2048 + d] = (unsigned short)bfs(sv);
    }
  }
}

// ---- KDE: G4 = E @ centers (intra-block K-split) / s + fused y epilogue ----
// 256 blocks = 128 col-groups (16 d) x 2 m-halves (32 b)
__global__ __launch_bounds__(256) void kde(const float* __restrict__ centers,
                                           const float* __restrict__ x,
                                           float* __restrict__ out,
                                           float* __restrict__ ws) {
  __shared__ f32x4 sacc[4][2][64];   // 8 KB
  __shared__ float sinv[64];
  int blk = blockIdx.x, t = threadIdx.x;
  int w = t >> 6, l = t & 63;
  int cs = blk >> 1, mh = blk & 1;
  int d0 = cs * 16, m0 = mh * 32;
  int ln = l & 15, lk = l >> 4;
  int k0 = w * 256;
  if (t < 64) {
    float s = 0.f;
#pragma unroll
    for (int i = 0; i < 64; ++i) s += ws[WS_SPART + i * 64 + t];
    sinv[t] = 1.0f / s;
  }
  const unsigned short* aptr =
      (const unsigned short*)(ws + WS_PROB) + (size_t)(m0 + ln) * 1024 + k0 + lk * 8;
  f32x4 acc0 = {0.f, 0.f, 0.f, 0.f}, acc1 = {0.f, 0.f, 0.f, 0.f};
  for (int ks = 0; ks < 8; ++ks) {
    short8 a0 = *(const short8*)(aptr + ks * 32);
    short8 a1 = *(const short8*)(aptr + 16 * 1024 + ks * 32);
    int kbase = k0 + ks * 32 + lk * 8;
    short8 bb;
#pragma unroll
    for (int j = 0; j < 8; ++j) {
      int kc = min(kbase + j, 999);
      bb[j] = bfs(centers[(size_t)kc * 2048 + d0 + ln]);
    }
    acc0 = MFMA(a0, bb, acc0);
    acc1 = MFMA(a1, bb, acc1);
  }
  sacc[w][0][l] = acc0;
  sacc[w][1][l] = acc1;
  __syncthreads();
  if (w == 0) {
    f32x4 r0 = sacc[0][0][l], r1 = sacc[0][1][l];
#pragma unroll
    for (int i = 1; i < 4; ++i) {
      f32x4 u0 = sacc[i][0][l], u1 = sacc[i][1][l];
      r0.x += u0.x; r0.y += u0.y; r0.z += u0.z; r0.w += u0.w;
      r1.x += u1.x; r1.y += u1.y; r1.z += u1.z; r1.w += u1.w;
    }
    const unsigned short* sel = (const unsigned short*)(ws + WS_SEL);
    unsigned short* xnb = (unsigned short*)(ws + WS_XNB);
    float rr[8] = {r0.x, r0.y, r0.z, r0.w, r1.x, r1.y, r1.z, r1.w};
#pragma unroll
    for (int q = 0; q < 8; ++q) {
      int b = m0 + (q >> 2) * 16 + lk * 4 + (q & 3);
      int d = d0 + ln;
      float cc = rr[q] * sinv[b];            // centers_cur = (E@centers)/s
      float sv = bf2f(sel[(size_t)b * 2048 + d]);
      float xv = x[(size_t)b * 2048 + d];
      float fast = sv * cc;
      out[195072 + (size_t)b * 2048 + d] = fast;
      float yv = xv + fast;                  // y (conf applied in k8)
      xnb[(size_t)b * 2048 + d] = (unsigned short)bfs(yv);
      float sq = yv * yv;
      sq += __shfl_xor(sq, 1);
      sq += __shfl_xor(sq, 2);
      sq += __shfl_xor(sq, 4);
      sq += __shfl_xor(sq, 8);
      if (ln == 0) ws[WS_XN2P + cs * 64 + b] = sq;
    }
  }
}

// ---- K7: G5 = y @ cosw^T + ||w||^2 partials; grid 128 = 32 x 4 ----
__global__ __launch_bounds__(256) void k7(const float* __restrict__ cosw,
                                          float* __restrict__ ws) {
  int blk = blockIdx.x, t = threadIdx.x;
  int w = t >> 6, l = t & 63;
  int colblk = blk & 31, ksplit = blk >> 5;
  int ln = l & 15, lk = l >> 4;
  int n = colblk * 32 + (w & 1) * 16 + ln;   // 0..1023
  int m0 = (w >> 1) * 32;
  int k0 = ksplit * 512;
  const float* bptr = cosw + (size_t)min(n, 999) * 2048 + k0 + lk * 8;
  const unsigned short* aptr =
      (const unsigned short*)(ws + WS_XNB) + (size_t)(m0 + ln) * 2048 + k0 + lk * 8;
  f32x4 acc0 = {0.f, 0.f, 0.f, 0.f}, acc1 = {0.f, 0.f, 0.f, 0.f};
  float sq = 0.f;
#pragma unroll 4
  for (int ks = 0; ks < 16; ++ks) {
    short8 a0 = *(const short8*)(aptr + ks * 32);
    short8 a1 = *(const short8*)(aptr + 16 * 2048 + ks * 32);
    float4 f0 = *(const float4*)(bptr + ks * 32);
    float4 f1 = *(const float4*)(bptr + ks * 32 + 4);
    sq += f0.x*f0.x + f0.y*f0.y + f0.z*f0.z + f0.w*f0.w
        + f1.x*f1.x + f1.y*f1.y + f1.z*f1.z + f1.w*f1.w;
    short8 bb;
    bb[0] = bfs(f0.x); bb[1] = bfs(f0.y); bb[2] = bfs(f0.z); bb[3] = bfs(f0.w);
    bb[4] = bfs(f1.x); bb[5] = bfs(f1.y); bb[6] = bfs(f1.z); bb[7] = bfs(f1.w);
    acc0 = MFMA(a0, bb, acc0);
    acc1 = MFMA(a1, bb, acc1);
  }
  float* P = ws + WS_P5 + ((size_t)ksplit * 1024 + n) * 68;
  *(f32x4*)(P + m0 + lk * 4) = acc0;
  *(f32x4*)(P + m0 + 16 + lk * 4) = acc1;
  sq += __shfl_xor(sq, 16);
  sq += __shfl_xor(sq, 32);
  if (w < 2 && l < 16) P[64] = sq;
}

// ---- K8: reduce P5 + conf-aware cosnorm epilogue -> logits ----
__global__ __launch_bounds__(256) void k8(float* __restrict__ out,
                                          const float* __restrict__ ws) {
  __shared__ float tile[64][65];
  __shared__ float scale[64];
  int blk = blockIdx.x, t = threadIdx.x, l = t & 63, w = t >> 6;
  int c0 = blk * 64;
  const size_t KS = (size_t)1024 * 68;
  if (t < 64) {
    float s = 0.f;
    for (int i = 0; i < 128; ++i) s += ws[WS_XN2P + i * 64 + t];
    float ny = sqrtf(fmaxf(s, 0.f));                       // ||y||
    float d2 = 3.0e38f;
    for (int i = 0; i < 64; ++i) d2 = fminf(d2, ws[WS_DMINP + i * 64 + t]);
    float cf = 10.0f * rsqrtf(fmaxf(d2, 1e-20f));          // conf
    scale[t] = 16.0f * cf / (1.0f + cf * ny);
  }
  __syncthreads();
  for (int cl = w; cl < 64; cl += 4) {
    int c = c0 + cl;
    const float* P = ws + WS_P5 + (size_t)c * 68;
    float v = P[l] + P[KS + l] + P[2*KS + l] + P[3*KS + l];
    float w2 = P[64] + P[KS + 64] + P[2*KS + 64] + P[3*KS + 64];
    tile[cl][l] = v * rsqrtf(fmaxf(w2, 1e-30f)) * scale[l];
  }
  __syncthreads();
  for (int r = 0; r < 16; ++r) {
    int b = w * 16 + r;
    int c = c0 + l;
    if (c < 1000) out[(size_t)b * 1000 + c] = tile[l][b];
  }
}

extern "C" void kernel_launch(void* const* d_in, const int* in_sizes, int n_in,
                              void* d_out, int out_size, void* d_ws, size_t ws_size,
                              hipStream_t stream) {
  const float* x       = (const float*)d_in[0];
  const float* centers = (const float*)d_in[2];
  const float* fcw     = (const float*)d_in[4];
  const float* fcb     = (const float*)d_in[5];
  const float* fc1w    = (const float*)d_in[6];
  const float* fc1b    = (const float*)d_in[7];
  const float* cosw    = (const float*)d_in[8];
  float* out = (float*)d_out;
  float* ws  = (float*)d_ws;

  hipLaunchKernelGGL(k1,  dim3(64),  dim3(256), 0, stream, x, out, ws);
  hipLaunchKernelGGL(k2,  dim3(256), dim3(256), 0, stream, centers, fc1w, fcw, fc1b, fcb, ws);
  hipLaunchKernelGGL(kde, dim3(256), dim3(256), 0, stream, centers, x, out, ws);
  hipLaunchKernelGGL(k7,  dim3(128), dim3(256), 0, stream, cosw, ws);
  hipLaunchKernelGGL(k8,  dim3(16),  dim3(256), 0, stream, out, ws);
}